// Round 18
// baseline (354.846 us; speedup 1.0000x reference)
//
#include <hip/hip_runtime.h>
#include <math.h>

#define N_NODES 12000
#define F_INN 16
#define HIDD 64
#define NCLUST 100
#define NEDGE 384000
#define NBLK_N 47
#define CAP 96
#define EPT 4
#define NBLK_E 375
#define NBLK_F1 (N_NODES / 4)          // 3000
#define NBLK_F2 (N_NODES / 8)          // 1500
#define NBIN 188
#define BINW 64
#define BCAP 2560
#define STCAP 24
#define NCOPY 5
#define NBLKA (NBLK_E + NBLK_N + 2)    // 424
#define NBLKB (NBIN + NBLK_N + NBLK_E) // 610
#define NBLKF2T (NBLK_F2 + 1)          // 1501

// ws layout (4-byte element offsets) — real (r17):
#define OFF_BINCNT  0        // 188 int (memset)
#define OFF_SCAL    188      // 2 f32   (memset)
#define ZERO_ELEMS  190
#define OFF_COUNT   192
#define OFF_SSPART  12192
#define OFF_NORM2   24224
#define OFF_W2TREL  36224
#define OFF_W2TROOT 42624
#define OFF_SMC     49024
#define OFF_H       241024
#define OFF_SRCW    1009024
#define OFF_BINBUF  3313024  // 188*2560 int2
// clones (diagnostic):
#define OFF_CBINCNT 4275584  // NCOPY*188 int (memset)
#define OFF_CSCAL   4276524  // 2 (memset)
#define CZERO_ELEMS 942
#define OFF_CCOUNT  4276526
#define OFF_CSSPART 4288526
#define OFF_CH      4300558
#define OFF_COUT    5068558
#define OFF_CSRCW   6268574  // 12000*96 int2 (shared clone)
#define OFF_CBINBUF 8572574  // NCOPY*188*2560 int2 -> ends ~53.5MB

// ---------------- pass A: edge binning | smc softmax+norm2 | W2 transpose (copy-aware)
__global__ void binA_kernel(const float* __restrict__ x, const int* __restrict__ ei,
                            const float* __restrict__ ew, float* __restrict__ smc,
                            float* __restrict__ norm2, int* __restrict__ bincnt0,
                            int2* __restrict__ binbuf0, const float* __restrict__ W2_rel,
                            const float* __restrict__ W2_root, float* __restrict__ w2t_rel,
                            float* __restrict__ w2t_root) {
    __shared__ int shmA[188 + 188 * STCAP * 2];
    int t = threadIdx.x;
    int copy = blockIdx.x / NBLKA;
    int b = blockIdx.x - copy * NBLKA;
    int* bincnt = bincnt0 + copy * 188;
    int2* binbuf = binbuf0 + (size_t)copy * (188 * BCAP);
    if (b < NBLK_E) {
        int* scnt = shmA;
        int2* sbuf = (int2*)(shmA + 188);
        for (int i = t; i < 188; i += 256) scnt[i] = 0;
        __syncthreads();
        int tid = b * 256 + t;
        int e0 = tid * EPT;
        int4 sv = *(const int4*)(ei + e0);
        int4 dv = *(const int4*)(ei + NEDGE + e0);
        float4 wv = *(const float4*)(ew + e0);
        int s[EPT] = {sv.x, sv.y, sv.z, sv.w};
        int d[EPT] = {dv.x, dv.y, dv.z, dv.w};
        float w[EPT] = {wv.x, wv.y, wv.z, wv.w};
#pragma unroll
        for (int i = 0; i < EPT; ++i) {
            int bin = d[i] >> 6;
            int dl = d[i] & 63;
            int2 rec = make_int2(s[i] | (dl << 16), __float_as_int(w[i]));
            int pos = atomicAdd(&scnt[bin], 1);
            if (pos < STCAP) {
                sbuf[bin * STCAP + pos] = rec;
            } else {
                int base = atomicAdd(&bincnt[bin], 1);
                binbuf[bin * BCAP + base] = rec;
            }
        }
        __syncthreads();
        if (t < 188) {
            int k = scnt[t];
            if (k > STCAP) k = STCAP;
            if (k > 0) {
                int base = atomicAdd(&bincnt[t], k);
                for (int i = 0; i < k; ++i) binbuf[t * BCAP + base + i] = sbuf[t * STCAP + i];
            }
        }
    } else if (b < NBLK_E + NBLK_N) {
        int i = (b - NBLK_E) * 256 + t;
        if (i >= N_NODES) return;
        const float4* xr = (const float4*)(x + i * 16);
        float4 r0 = xr[0], r1 = xr[1], r2 = xr[2], r3 = xr[3];
        float v[16] = {r0.x, r0.y, r0.z, r0.w, r1.x, r1.y, r1.z, r1.w,
                       r2.x, r2.y, r2.z, r2.w, r3.x, r3.y, r3.z, r3.w};
        float m = v[0];
#pragma unroll
        for (int k = 1; k < 16; ++k) m = fmaxf(m, v[k]);
        float s = 0.f;
#pragma unroll
        for (int k = 0; k < 16; ++k) { v[k] = __expf(v[k] - m); s += v[k]; }
        float inv = 1.f / s;
        float n2 = 0.f;
#pragma unroll
        for (int k = 0; k < 16; ++k) { v[k] *= inv; n2 += v[k] * v[k]; }
        float4* so = (float4*)(smc + i * 16);
        so[0] = make_float4(v[0], v[1], v[2], v[3]);
        so[1] = make_float4(v[4], v[5], v[6], v[7]);
        so[2] = make_float4(v[8], v[9], v[10], v[11]);
        so[3] = make_float4(v[12], v[13], v[14], v[15]);
        norm2[i] = n2;
    } else {
        float* fl = (float*)shmA;
        const float* src = (b == NBLK_E + NBLK_N) ? W2_rel : W2_root;
        float* dst = (b == NBLK_E + NBLK_N) ? w2t_rel : w2t_root;
        for (int i = t; i < 6400; i += 256) fl[i] = src[i];
        __syncthreads();
        for (int j = t; j < 6400; j += 256) {
            int kk = j / 100, cl = j - kk * 100;
            dst[j] = fl[cl * 64 + kk];
        }
    }
}

// ---------------- pass B: per-bin LDS bucketize | ss partials | mincut (copy-aware via mod)
__global__ void binB_kernel(const int2* __restrict__ binbuf, const int* __restrict__ bincnt,
                            int* __restrict__ count, int2* __restrict__ srcw,
                            const float* __restrict__ smc, float* __restrict__ sspart,
                            const int* __restrict__ ei, const float* __restrict__ ew,
                            const float* __restrict__ norm2, float* __restrict__ scal) {
    __shared__ int shmB[64 + 64 * CAP * 2];
    int t = threadIdx.x;
    int b = blockIdx.x % NBLKB;
    if (b < NBIN) {
        int* cnt = shmB;
        int2* lbuck = (int2*)(shmB + 64);
        for (int i = t; i < 64; i += 256) cnt[i] = 0;
        __syncthreads();
        int nE = bincnt[b];
        const int2* bp = binbuf + b * BCAP;
        for (int i = t; i < nE; i += 256) {
            int2 rec = bp[i];
            int src = rec.x & 0xFFFF;
            int dl = rec.x >> 16;
            int pos = atomicAdd(&cnt[dl], 1);
            if (pos < CAP) lbuck[dl * CAP + pos] = make_int2(src, rec.y);
        }
        __syncthreads();
        int nbase = b * BINW;
        int nvalid = N_NODES - nbase;
        if (nvalid > BINW) nvalid = BINW;
        if (t < nvalid) count[nbase + t] = cnt[t];
        int lim = nvalid * CAP;
        int2* out = srcw + (size_t)nbase * CAP;
        for (int i = t; i < lim; i += 256) out[i] = lbuck[i];
    } else if (b < NBIN + NBLK_N) {
        int bb = b - NBIN;
        float* rows = (float*)shmB;
        int n = bb * 256 + t;
        float* rp = rows + t * 17;
        if (n < N_NODES) {
            const float4* sr = (const float4*)(smc + n * 16);
            float4 a0 = sr[0], a1 = sr[1], a2v = sr[2], a3 = sr[3];
            rp[0] = a0.x;  rp[1] = a0.y;  rp[2] = a0.z;  rp[3] = a0.w;
            rp[4] = a1.x;  rp[5] = a1.y;  rp[6] = a1.z;  rp[7] = a1.w;
            rp[8] = a2v.x; rp[9] = a2v.y; rp[10] = a2v.z; rp[11] = a2v.w;
            rp[12] = a3.x; rp[13] = a3.y; rp[14] = a3.z; rp[15] = a3.w;
        } else {
#pragma unroll
            for (int k = 0; k < 16; ++k) rp[k] = 0.f;
        }
        __syncthreads();
        int a = t & 15, bq = t >> 4;
        float accs = 0.f;
#pragma unroll 4
        for (int r = 0; r < 256; ++r)
            accs = fmaf(rows[r * 17 + a], rows[r * 17 + bq], accs);
        sspart[bb * 256 + t] = accs;
    } else {
        int tid = (b - NBIN - NBLK_N) * 256 + t;
        int e0 = tid * EPT;
        int4 sv = *(const int4*)(ei + e0);
        int4 dv = *(const int4*)(ei + NEDGE + e0);
        float4 wv = *(const float4*)(ew + e0);
        int s[EPT] = {sv.x, sv.y, sv.z, sv.w};
        int d[EPT] = {dv.x, dv.y, dv.z, dv.w};
        float w[EPT] = {wv.x, wv.y, wv.z, wv.w};
        float np = 0.f, dp = 0.f;
#pragma unroll
        for (int i = 0; i < EPT; ++i) {
            const float4* ps = (const float4*)(smc + s[i] * 16);
            const float4* pd = (const float4*)(smc + d[i] * 16);
            float4 s0 = ps[0], s1 = ps[1], s2 = ps[2], s3 = ps[3];
            float4 d0 = pd[0], d1 = pd[1], d2 = pd[2], d3 = pd[3];
            float dot = s0.x * d0.x + s0.y * d0.y + s0.z * d0.z + s0.w * d0.w +
                        s1.x * d1.x + s1.y * d1.y + s1.z * d1.z + s1.w * d1.w +
                        s2.x * d2.x + s2.y * d2.y + s2.z * d2.z + s2.w * d2.w +
                        s3.x * d3.x + s3.y * d3.y + s3.z * d3.z + s3.w * d3.w;
            np = fmaf(w[i], dot, np);
            dp = fmaf(w[i], norm2[s[i]], dp);
        }
        float* redn = (float*)shmB;
        float* redd = (float*)shmB + 256;
        redn[t] = np;
        redd[t] = dp;
        __syncthreads();
        for (int s2 = 128; s2 > 0; s2 >>= 1) {
            if (t < s2) { redn[t] += redn[t + s2]; redd[t] += redd[t + s2]; }
            __syncthreads();
        }
        if (t == 0) {
            atomicAdd(&scal[0], redn[0]);
            atomicAdd(&scal[1], redd[0]);
        }
    }
}

// ---------------- fused layer 1 (pure) — r17 body (copy-aware via mod)
__global__ void fused1_kernel(const float* __restrict__ x, const int2* __restrict__ srcw,
                              const int* __restrict__ count, const float* __restrict__ W1_rel,
                              const float* __restrict__ W1_root, const float* __restrict__ b1,
                              float* __restrict__ h) {
    __shared__ float shm[2304];
    int t = threadIdx.x;
    int b = blockIdx.x % NBLK_F1;
    float* wrelT  = shm;
    float* wrootT = shm + 1024;
    float* b1s    = shm + 2048;
    float* aggr   = shm + 2112;
    float* xs     = shm + 2176;
    for (int idx = t; idx < 1024; idx += 256) {
        int f = idx >> 4, k = idx & 15;
        wrelT[(k << 6) + f]  = W1_rel[idx];
        wrootT[(k << 6) + f] = W1_root[idx];
    }
    if (t < 64) b1s[t] = b1[t];
    int w = t >> 6, lane = t & 63;
    int j2 = lane >> 2;
    int q  = lane & 3;
    int n = b * 4 + w;
    int len = count[n];
    const int2* bucket = srcw + n * CAP;
    float4 acc4 = make_float4(0.f, 0.f, 0.f, 0.f);
    for (int k = 0; k < len; k += 32) {
        int ia = k + j2, ib = k + 16 + j2;
        int2 pa = bucket[ia];
        int2 pb = bucket[ib];
        if (ia >= len) pa = make_int2(0, 0);
        if (ib >= len) pb = make_int2(0, 0);
        float4 va = *(const float4*)(x + pa.x * 16 + q * 4);
        float4 vb = *(const float4*)(x + pb.x * 16 + q * 4);
        float wa = __int_as_float(pa.y), wb = __int_as_float(pb.y);
        acc4.x = fmaf(va.x, wa, acc4.x); acc4.y = fmaf(va.y, wa, acc4.y);
        acc4.z = fmaf(va.z, wa, acc4.z); acc4.w = fmaf(va.w, wa, acc4.w);
        acc4.x = fmaf(vb.x, wb, acc4.x); acc4.y = fmaf(vb.y, wb, acc4.y);
        acc4.z = fmaf(vb.z, wb, acc4.z); acc4.w = fmaf(vb.w, wb, acc4.w);
    }
    acc4.x += __shfl_xor(acc4.x, 4);  acc4.y += __shfl_xor(acc4.y, 4);
    acc4.z += __shfl_xor(acc4.z, 4);  acc4.w += __shfl_xor(acc4.w, 4);
    acc4.x += __shfl_xor(acc4.x, 8);  acc4.y += __shfl_xor(acc4.y, 8);
    acc4.z += __shfl_xor(acc4.z, 8);  acc4.w += __shfl_xor(acc4.w, 8);
    acc4.x += __shfl_xor(acc4.x, 16); acc4.y += __shfl_xor(acc4.y, 16);
    acc4.z += __shfl_xor(acc4.z, 16); acc4.w += __shfl_xor(acc4.w, 16);
    acc4.x += __shfl_xor(acc4.x, 32); acc4.y += __shfl_xor(acc4.y, 32);
    acc4.z += __shfl_xor(acc4.z, 32); acc4.w += __shfl_xor(acc4.w, 32);
    if (j2 == 0) *(float4*)(aggr + w * 16 + q * 4) = acc4;
    if (lane < 16) xs[w * 16 + lane] = x[n * 16 + lane];
    __syncthreads();
    float o = b1s[lane];
#pragma unroll
    for (int kk = 0; kk < 16; ++kk)
        o = fmaf(aggr[w * 16 + kk], wrelT[(kk << 6) + lane],
                 fmaf(xs[w * 16 + kk], wrootT[(kk << 6) + lane], o));
    h[n * 64 + lane] = fmaxf(o, 0.f);
}

// ---------------- fused layer 2 + finalize — r17 body (copy-aware via mod)
__global__ __launch_bounds__(512) void fused2_finalize_kernel(
    const float* __restrict__ h, const int2* __restrict__ srcw, const int* __restrict__ count,
    const float* __restrict__ w2t_rel, const float* __restrict__ w2t_root,
    const float* __restrict__ b2, float* __restrict__ out, const float* __restrict__ sspart,
    const float* __restrict__ scal) {
    __shared__ float wsrel[6400];
    __shared__ float a2[8][64], hrow[8][64];
    __shared__ float logits[8][104];
    __shared__ float b2s[104];
    int t = threadIdx.x;
    int b = blockIdx.x % NBLKF2T;
    if (b < NBLK_F2) {
        for (int i = t; i < 6400; i += 512) wsrel[i] = w2t_rel[i];
        if (t < NCLUST) b2s[t] = b2[t];
        int nn = t >> 6;
        int c = t & 63;
        int eslot = c >> 4;
        int q = c & 15;
        int n = b * 8 + nn;
        int len = count[n];
        const int2* bucket = srcw + n * CAP;
        float4 acc4 = make_float4(0.f, 0.f, 0.f, 0.f);
        for (int k = 0; k < len; k += 32) {
            int i0 = k + eslot,      i1 = k + 4 + eslot;
            int i2 = k + 8 + eslot,  i3 = k + 12 + eslot;
            int i4 = k + 16 + eslot, i5 = k + 20 + eslot;
            int i6 = k + 24 + eslot, i7 = k + 28 + eslot;
            int2 pa = bucket[i0]; int2 pb = bucket[i1];
            int2 pc = bucket[i2]; int2 pd = bucket[i3];
            int2 pe = bucket[i4]; int2 pf = bucket[i5];
            int2 pg = bucket[i6]; int2 ph = bucket[i7];
            if (i0 >= len) pa = make_int2(0, 0);
            if (i1 >= len) pb = make_int2(0, 0);
            if (i2 >= len) pc = make_int2(0, 0);
            if (i3 >= len) pd = make_int2(0, 0);
            if (i4 >= len) pe = make_int2(0, 0);
            if (i5 >= len) pf = make_int2(0, 0);
            if (i6 >= len) pg = make_int2(0, 0);
            if (i7 >= len) ph = make_int2(0, 0);
            float4 va = *(const float4*)(h + pa.x * 64 + q * 4);
            float4 vb = *(const float4*)(h + pb.x * 64 + q * 4);
            float4 vc = *(const float4*)(h + pc.x * 64 + q * 4);
            float4 vd = *(const float4*)(h + pd.x * 64 + q * 4);
            float4 ve = *(const float4*)(h + pe.x * 64 + q * 4);
            float4 vf = *(const float4*)(h + pf.x * 64 + q * 4);
            float4 vg = *(const float4*)(h + pg.x * 64 + q * 4);
            float4 vh = *(const float4*)(h + ph.x * 64 + q * 4);
            float wa = __int_as_float(pa.y), wb = __int_as_float(pb.y);
            float wc = __int_as_float(pc.y), wd = __int_as_float(pd.y);
            float we = __int_as_float(pe.y), wf = __int_as_float(pf.y);
            float wg = __int_as_float(pg.y), wh = __int_as_float(ph.y);
            acc4.x = fmaf(va.x, wa, acc4.x); acc4.y = fmaf(va.y, wa, acc4.y);
            acc4.z = fmaf(va.z, wa, acc4.z); acc4.w = fmaf(va.w, wa, acc4.w);
            acc4.x = fmaf(vb.x, wb, acc4.x); acc4.y = fmaf(vb.y, wb, acc4.y);
            acc4.z = fmaf(vb.z, wb, acc4.z); acc4.w = fmaf(vb.w, wb, acc4.w);
            acc4.x = fmaf(vc.x, wc, acc4.x); acc4.y = fmaf(vc.y, wc, acc4.y);
            acc4.z = fmaf(vc.z, wc, acc4.z); acc4.w = fmaf(vc.w, wc, acc4.w);
            acc4.x = fmaf(vd.x, wd, acc4.x); acc4.y = fmaf(vd.y, wd, acc4.y);
            acc4.z = fmaf(vd.z, wd, acc4.z); acc4.w = fmaf(vd.w, wd, acc4.w);
            acc4.x = fmaf(ve.x, we, acc4.x); acc4.y = fmaf(ve.y, we, acc4.y);
            acc4.z = fmaf(ve.z, we, acc4.z); acc4.w = fmaf(ve.w, we, acc4.w);
            acc4.x = fmaf(vf.x, wf, acc4.x); acc4.y = fmaf(vf.y, wf, acc4.y);
            acc4.z = fmaf(vf.z, wf, acc4.z); acc4.w = fmaf(vf.w, wf, acc4.w);
            acc4.x = fmaf(vg.x, wg, acc4.x); acc4.y = fmaf(vg.y, wg, acc4.y);
            acc4.z = fmaf(vg.z, wg, acc4.z); acc4.w = fmaf(vg.w, wg, acc4.w);
            acc4.x = fmaf(vh.x, wh, acc4.x); acc4.y = fmaf(vh.y, wh, acc4.y);
            acc4.z = fmaf(vh.z, wh, acc4.z); acc4.w = fmaf(vh.w, wh, acc4.w);
        }
        acc4.x += __shfl_xor(acc4.x, 16); acc4.y += __shfl_xor(acc4.y, 16);
        acc4.z += __shfl_xor(acc4.z, 16); acc4.w += __shfl_xor(acc4.w, 16);
        acc4.x += __shfl_xor(acc4.x, 32); acc4.y += __shfl_xor(acc4.y, 32);
        acc4.z += __shfl_xor(acc4.z, 32); acc4.w += __shfl_xor(acc4.w, 32);
        if (eslot == 0) *(float4*)(&a2[nn][q * 4]) = acc4;
        hrow[nn][c] = h[n * 64 + c];
        __syncthreads();
        int g = t >> 7, c2 = t & 127;
        if (c2 < NCLUST) {
            int na = 2 * g, nb2 = 2 * g + 1;
            float s0 = b2s[c2], s1 = s0;
#pragma unroll 8
            for (int kk = 0; kk < 64; ++kk) {
                float wr = wsrel[kk * 100 + c2];
                float wo = w2t_root[kk * 100 + c2];
                s0 = fmaf(a2[na][kk], wr, fmaf(hrow[na][kk], wo, s0));
                s1 = fmaf(a2[nb2][kk], wr, fmaf(hrow[nb2][kk], wo, s1));
            }
            logits[na][c2] = s0;
            logits[nb2][c2] = s1;
        }
        __syncthreads();
        float v0 = logits[nn][c];
        float v1 = (c < NCLUST - 64) ? logits[nn][64 + c] : -INFINITY;
        float m = fmaxf(v0, v1);
#pragma unroll
        for (int off = 32; off > 0; off >>= 1) m = fmaxf(m, __shfl_xor(m, off));
        float e0 = __expf(v0 - m);
        float e1 = (c < NCLUST - 64) ? __expf(v1 - m) : 0.f;
        float s = e0 + e1;
#pragma unroll
        for (int off = 32; off > 0; off >>= 1) s += __shfl_xor(s, off);
        float inv = 1.f / s;
        out[n * NCLUST + c] = e0 * inv;
        if (c < NCLUST - 64) out[n * NCLUST + 64 + c] = e1 * inv;
    } else {
        float* red = wsrel;
        float sv = 0.f;
        if (t < 256)
            for (int bb = 0; bb < NBLK_N; ++bb) sv += sspart[bb * 256 + t];
        red[t] = sv * sv;
        __syncthreads();
        for (int s = 256; s > 0; s >>= 1) {
            if (t < s) red[t] += red[t + s];
            __syncthreads();
        }
        float ssnorm = sqrtf(red[0]);
        __syncthreads();
        float diff = (t < 256) ? (sv / ssnorm - ((t % 17 == 0) ? 0.25f : 0.f)) : 0.f;
        red[t] = diff * diff;
        __syncthreads();
        for (int s = 256; s > 0; s >>= 1) {
            if (t < s) red[t] += red[t + s];
            __syncthreads();
        }
        if (t == 0) {
            out[N_NODES * NCLUST + 0] = -(scal[0] / scal[1]);
            out[N_NODES * NCLUST + 1] = sqrtf(red[0]);
        }
    }
}

extern "C" void kernel_launch(void* const* d_in, const int* in_sizes, int n_in,
                              void* d_out, int out_size, void* d_ws, size_t ws_size,
                              hipStream_t stream) {
    const float* x       = (const float*)d_in[0];
    const int*   ei      = (const int*)d_in[1];
    const float* ew      = (const float*)d_in[2];
    const float* W1_rel  = (const float*)d_in[3];
    const float* W1_root = (const float*)d_in[4];
    const float* b1      = (const float*)d_in[5];
    const float* W2_rel  = (const float*)d_in[6];
    const float* W2_root = (const float*)d_in[7];
    const float* b2      = (const float*)d_in[8];
    float* out = (float*)d_out;
    int*   wsi = (int*)d_ws;

    int*   bincnt  = wsi + OFF_BINCNT;
    float* scal    = (float*)(wsi + OFF_SCAL);
    int*   count   = wsi + OFF_COUNT;
    float* sspart  = (float*)(wsi + OFF_SSPART);
    float* norm2   = (float*)(wsi + OFF_NORM2);
    float* w2trel  = (float*)(wsi + OFF_W2TREL);
    float* w2troot = (float*)(wsi + OFF_W2TROOT);
    float* smc     = (float*)(wsi + OFF_SMC);
    float* h       = (float*)(wsi + OFF_H);
    int2*  srcw    = (int2*)(wsi + OFF_SRCW);
    int2*  binbuf  = (int2*)(wsi + OFF_BINBUF);
    // clones
    int*   cbincnt = wsi + OFF_CBINCNT;
    float* cscal   = (float*)(wsi + OFF_CSCAL);
    int*   ccount  = wsi + OFF_CCOUNT;
    float* csspart = (float*)(wsi + OFF_CSSPART);
    float* ch      = (float*)(wsi + OFF_CH);
    float* cout    = (float*)(wsi + OFF_COUT);
    int2*  csrcw   = (int2*)(wsi + OFF_CSRCW);
    int2*  cbinbuf = (int2*)(wsi + OFF_CBINBUF);

    hipMemsetAsync(wsi, 0, ZERO_ELEMS * sizeof(int), stream);
    hipMemsetAsync(wsi + OFF_CBINCNT, 0, CZERO_ELEMS * sizeof(int), stream);

    // real pipeline (r17 exact)
    binA_kernel<<<NBLKA, 256, 0, stream>>>(x, ei, ew, smc, norm2, bincnt, binbuf,
                                           W2_rel, W2_root, w2trel, w2troot);
    // DIAG: binA x5 -> per-copy clone bincnt/binbuf
    binA_kernel<<<NCOPY * NBLKA, 256, 0, stream>>>(x, ei, ew, smc, norm2, cbincnt, cbinbuf,
                                                   W2_rel, W2_root, w2trel, w2troot);
    binB_kernel<<<NBLKB, 256, 0, stream>>>(binbuf, bincnt, count, srcw,
                                           smc, sspart, ei, ew, norm2, scal);
    // DIAG: binB x5 (reads real binbuf; writes clones)
    binB_kernel<<<NCOPY * NBLKB, 256, 0, stream>>>(binbuf, bincnt, ccount, csrcw,
                                                   smc, csspart, ei, ew, norm2, cscal);
    fused1_kernel<<<NBLK_F1, 256, 0, stream>>>(x, srcw, count, W1_rel, W1_root, b1, h);
    // DIAG: f1 x5 (writes clone h)
    fused1_kernel<<<NCOPY * NBLK_F1, 256, 0, stream>>>(x, srcw, count, W1_rel, W1_root, b1, ch);
    fused2_finalize_kernel<<<NBLKF2T, 512, 0, stream>>>(h, srcw, count, w2trel, w2troot,
                                                        b2, out, sspart, scal);
    // DIAG: f2 x5 (writes clone out)
    fused2_finalize_kernel<<<NCOPY * NBLKF2T, 512, 0, stream>>>(h, srcw, count, w2trel, w2troot,
                                                                b2, cout, sspart, scal);
}

// Round 19
// 92.320 us; speedup vs baseline: 3.8437x; 3.8437x over previous
//
#include <hip/hip_runtime.h>
#include <math.h>

#define N_NODES 12000
#define F_INN 16
#define HIDD 64
#define NCLUST 100
#define NEDGE 384000
#define NBLK_N 47
#define CAP 96
#define EPT 4
#define NBLK_E 375
#define NBLK_F2 (N_NODES / 8)          // 1500
#define NBIN 188
#define BINW 64
#define BCAP 2560
#define STCAP 24

// ws layout (4-byte element offsets) — r17:
#define OFF_BINCNT  0        // 188 int (memset)
#define OFF_SCAL    188      // 2 f32   (memset)
#define ZERO_ELEMS  190
#define OFF_COUNT   192
#define OFF_SSPART  12192
#define OFF_NORM2   24224
#define OFF_W2TREL  36224
#define OFF_W2TROOT 42624
#define OFF_SMC     49024
#define OFF_H       241024
#define OFF_SRCW    1009024
#define OFF_BINBUF  3313024  // 188*2560 int2

// ---------------- pass A: edge binning | smc softmax+norm2 | W2 transpose (r17 exact)
__global__ void binA_kernel(const float* __restrict__ x, const int* __restrict__ ei,
                            const float* __restrict__ ew, float* __restrict__ smc,
                            float* __restrict__ norm2, int* __restrict__ bincnt,
                            int2* __restrict__ binbuf, const float* __restrict__ W2_rel,
                            const float* __restrict__ W2_root, float* __restrict__ w2t_rel,
                            float* __restrict__ w2t_root) {
    __shared__ int shmA[188 + 188 * STCAP * 2];
    int t = threadIdx.x;
    int b = blockIdx.x;
    if (b < NBLK_E) {
        int* scnt = shmA;
        int2* sbuf = (int2*)(shmA + 188);
        for (int i = t; i < 188; i += 256) scnt[i] = 0;
        __syncthreads();
        int tid = b * 256 + t;
        int e0 = tid * EPT;
        int4 sv = *(const int4*)(ei + e0);
        int4 dv = *(const int4*)(ei + NEDGE + e0);
        float4 wv = *(const float4*)(ew + e0);
        int s[EPT] = {sv.x, sv.y, sv.z, sv.w};
        int d[EPT] = {dv.x, dv.y, dv.z, dv.w};
        float w[EPT] = {wv.x, wv.y, wv.z, wv.w};
#pragma unroll
        for (int i = 0; i < EPT; ++i) {
            int bin = d[i] >> 6;
            int dl = d[i] & 63;
            int2 rec = make_int2(s[i] | (dl << 16), __float_as_int(w[i]));
            int pos = atomicAdd(&scnt[bin], 1);
            if (pos < STCAP) {
                sbuf[bin * STCAP + pos] = rec;
            } else {
                int base = atomicAdd(&bincnt[bin], 1);
                binbuf[bin * BCAP + base] = rec;
            }
        }
        __syncthreads();
        if (t < 188) {
            int k = scnt[t];
            if (k > STCAP) k = STCAP;
            if (k > 0) {
                int base = atomicAdd(&bincnt[t], k);
                for (int i = 0; i < k; ++i) binbuf[t * BCAP + base + i] = sbuf[t * STCAP + i];
            }
        }
    } else if (b < NBLK_E + NBLK_N) {
        int i = (b - NBLK_E) * 256 + t;
        if (i >= N_NODES) return;
        const float4* xr = (const float4*)(x + i * 16);
        float4 r0 = xr[0], r1 = xr[1], r2 = xr[2], r3 = xr[3];
        float v[16] = {r0.x, r0.y, r0.z, r0.w, r1.x, r1.y, r1.z, r1.w,
                       r2.x, r2.y, r2.z, r2.w, r3.x, r3.y, r3.z, r3.w};
        float m = v[0];
#pragma unroll
        for (int k = 1; k < 16; ++k) m = fmaxf(m, v[k]);
        float s = 0.f;
#pragma unroll
        for (int k = 0; k < 16; ++k) { v[k] = __expf(v[k] - m); s += v[k]; }
        float inv = 1.f / s;
        float n2 = 0.f;
#pragma unroll
        for (int k = 0; k < 16; ++k) { v[k] *= inv; n2 += v[k] * v[k]; }
        float4* so = (float4*)(smc + i * 16);
        so[0] = make_float4(v[0], v[1], v[2], v[3]);
        so[1] = make_float4(v[4], v[5], v[6], v[7]);
        so[2] = make_float4(v[8], v[9], v[10], v[11]);
        so[3] = make_float4(v[12], v[13], v[14], v[15]);
        norm2[i] = n2;
    } else {
        float* fl = (float*)shmA;
        const float* src = (b == NBLK_E + NBLK_N) ? W2_rel : W2_root;
        float* dst = (b == NBLK_E + NBLK_N) ? w2t_rel : w2t_root;
        for (int i = t; i < 6400; i += 256) fl[i] = src[i];
        __syncthreads();
        for (int j = t; j < 6400; j += 256) {
            int kk = j / 100, cl = j - kk * 100;
            dst[j] = fl[cl * 64 + kk];
        }
    }
}

// ---------------- merged pass B + fused1: per-bin LDS bucketize -> srcw/count write +
// f1 aggregation straight from LDS buckets | ss partials | mincut
__global__ void binBF1_kernel(const int2* __restrict__ binbuf, const int* __restrict__ bincnt,
                              int* __restrict__ count, int2* __restrict__ srcw,
                              const float* __restrict__ x, const float* __restrict__ W1_rel,
                              const float* __restrict__ W1_root, const float* __restrict__ b1,
                              float* __restrict__ h, const float* __restrict__ smc,
                              float* __restrict__ sspart, const int* __restrict__ ei,
                              const float* __restrict__ ew, const float* __restrict__ norm2,
                              float* __restrict__ scal) {
    __shared__ int shmU[64 + 64 * CAP * 2];   // cnt[64] + lbuck[64][96] int2 (49.4 KB)
    __shared__ float wrelT[1024], wrootT[1024], b1s[64];   // +8.5 KB -> 57.9 KB total
    int t = threadIdx.x;
    int b = blockIdx.x;
    if (b < NBIN) {
        int* cnt = shmU;
        int2* lbuck = (int2*)(shmU + 64);
        for (int idx = t; idx < 1024; idx += 256) {
            int f = idx >> 4, k = idx & 15;
            wrelT[(k << 6) + f]  = W1_rel[idx];
            wrootT[(k << 6) + f] = W1_root[idx];
        }
        if (t < 64) b1s[t] = b1[t];
        for (int i = t; i < 64; i += 256) cnt[i] = 0;
        __syncthreads();
        int nE = bincnt[b];
        const int2* bp = binbuf + b * BCAP;
        for (int i = t; i < nE; i += 256) {     // coalesced bin read, LDS-atomic bucketize
            int2 rec = bp[i];
            int src = rec.x & 0xFFFF;
            int dl = rec.x >> 16;
            int pos = atomicAdd(&cnt[dl], 1);
            if (pos < CAP) lbuck[dl * CAP + pos] = make_int2(src, rec.y);
        }
        __syncthreads();
        int nbase = b * BINW;
        int nvalid = N_NODES - nbase;
        if (nvalid > BINW) nvalid = BINW;
        if (t < nvalid) count[nbase + t] = cnt[t];
        int lim = nvalid * CAP;
        int2* outp = srcw + (size_t)nbase * CAP;
        for (int i = t; i < lim; i += 256) outp[i] = lbuck[i];   // coalesced (f2 needs it)
        // ---- fused layer 1 from LDS buckets: wave-per-node, 16 nodes/wave
        int w = t >> 6, lane = t & 63;
        int j2 = lane >> 2;   // edge slot 0..15
        int q  = lane & 3;    // float4 chunk of the 16-float x row
        for (int ni = w; ni < nvalid; ni += 4) {
            int n = nbase + ni;
            int len = cnt[ni];
            const int2* bucket = lbuck + ni * CAP;   // LDS reads
            float4 acc4 = make_float4(0.f, 0.f, 0.f, 0.f);
            for (int k = 0; k < len; k += 32) {      // predicated full-width batches (r17 order)
                int ia = k + j2, ib = k + 16 + j2;
                int2 pa = bucket[ia];
                int2 pb = bucket[ib];
                if (ia >= len) pa = make_int2(0, 0);
                if (ib >= len) pb = make_int2(0, 0);
                float4 va = *(const float4*)(x + pa.x * 16 + q * 4);
                float4 vb = *(const float4*)(x + pb.x * 16 + q * 4);
                float wa = __int_as_float(pa.y), wb = __int_as_float(pb.y);
                acc4.x = fmaf(va.x, wa, acc4.x); acc4.y = fmaf(va.y, wa, acc4.y);
                acc4.z = fmaf(va.z, wa, acc4.z); acc4.w = fmaf(va.w, wa, acc4.w);
                acc4.x = fmaf(vb.x, wb, acc4.x); acc4.y = fmaf(vb.y, wb, acc4.y);
                acc4.z = fmaf(vb.z, wb, acc4.z); acc4.w = fmaf(vb.w, wb, acc4.w);
            }
            acc4.x += __shfl_xor(acc4.x, 4);  acc4.y += __shfl_xor(acc4.y, 4);
            acc4.z += __shfl_xor(acc4.z, 4);  acc4.w += __shfl_xor(acc4.w, 4);
            acc4.x += __shfl_xor(acc4.x, 8);  acc4.y += __shfl_xor(acc4.y, 8);
            acc4.z += __shfl_xor(acc4.z, 8);  acc4.w += __shfl_xor(acc4.w, 8);
            acc4.x += __shfl_xor(acc4.x, 16); acc4.y += __shfl_xor(acc4.y, 16);
            acc4.z += __shfl_xor(acc4.z, 16); acc4.w += __shfl_xor(acc4.w, 16);
            acc4.x += __shfl_xor(acc4.x, 32); acc4.y += __shfl_xor(acc4.y, 32);
            acc4.z += __shfl_xor(acc4.z, 32); acc4.w += __shfl_xor(acc4.w, 32);
            // aggr[kk] == component (kk&3) of acc4 on lane (kk>>2)  (== r17 aggr layout)
            float xv = (lane < 16) ? x[n * 16 + lane] : 0.f;
            float o = b1s[lane];
#define F1STEP(KK, COMP) { float ag = __shfl(acc4.COMP, (KK) >> 2);            \
                           float xb = __shfl(xv, (KK));                        \
                           o = fmaf(ag, wrelT[((KK) << 6) + lane],             \
                                    fmaf(xb, wrootT[((KK) << 6) + lane], o)); }
            F1STEP(0, x)  F1STEP(1, y)  F1STEP(2, z)  F1STEP(3, w)
            F1STEP(4, x)  F1STEP(5, y)  F1STEP(6, z)  F1STEP(7, w)
            F1STEP(8, x)  F1STEP(9, y)  F1STEP(10, z) F1STEP(11, w)
            F1STEP(12, x) F1STEP(13, y) F1STEP(14, z) F1STEP(15, w)
#undef F1STEP
            h[n * 64 + lane] = fmaxf(o, 0.f);
        }
    } else if (b < NBIN + NBLK_N) {
        // ---- ss partials (S^T S) — r17 exact
        int bb = b - NBIN;
        float* rows = (float*)shmU;            // 256*17
        int n = bb * 256 + t;
        float* rp = rows + t * 17;
        if (n < N_NODES) {
            const float4* sr = (const float4*)(smc + n * 16);
            float4 a0 = sr[0], a1 = sr[1], a2v = sr[2], a3 = sr[3];
            rp[0] = a0.x;  rp[1] = a0.y;  rp[2] = a0.z;  rp[3] = a0.w;
            rp[4] = a1.x;  rp[5] = a1.y;  rp[6] = a1.z;  rp[7] = a1.w;
            rp[8] = a2v.x; rp[9] = a2v.y; rp[10] = a2v.z; rp[11] = a2v.w;
            rp[12] = a3.x; rp[13] = a3.y; rp[14] = a3.z; rp[15] = a3.w;
        } else {
#pragma unroll
            for (int k = 0; k < 16; ++k) rp[k] = 0.f;
        }
        __syncthreads();
        int a = t & 15, bq = t >> 4;
        float accs = 0.f;
#pragma unroll 4
        for (int r = 0; r < 256; ++r)
            accs = fmaf(rows[r * 17 + a], rows[r * 17 + bq], accs);
        sspart[bb * 256 + t] = accs;
    } else {
        // ---- mincut num/den edge reduction — r17 exact
        int tid = (b - NBIN - NBLK_N) * 256 + t;
        int e0 = tid * EPT;
        int4 sv = *(const int4*)(ei + e0);
        int4 dv = *(const int4*)(ei + NEDGE + e0);
        float4 wv = *(const float4*)(ew + e0);
        int s[EPT] = {sv.x, sv.y, sv.z, sv.w};
        int d[EPT] = {dv.x, dv.y, dv.z, dv.w};
        float w[EPT] = {wv.x, wv.y, wv.z, wv.w};
        float np = 0.f, dp = 0.f;
#pragma unroll
        for (int i = 0; i < EPT; ++i) {
            const float4* ps = (const float4*)(smc + s[i] * 16);
            const float4* pd = (const float4*)(smc + d[i] * 16);
            float4 s0 = ps[0], s1 = ps[1], s2 = ps[2], s3 = ps[3];
            float4 d0 = pd[0], d1 = pd[1], d2 = pd[2], d3 = pd[3];
            float dot = s0.x * d0.x + s0.y * d0.y + s0.z * d0.z + s0.w * d0.w +
                        s1.x * d1.x + s1.y * d1.y + s1.z * d1.z + s1.w * d1.w +
                        s2.x * d2.x + s2.y * d2.y + s2.z * d2.z + s2.w * d2.w +
                        s3.x * d3.x + s3.y * d3.y + s3.z * d3.z + s3.w * d3.w;
            np = fmaf(w[i], dot, np);
            dp = fmaf(w[i], norm2[s[i]], dp);
        }
        float* redn = (float*)shmU;
        float* redd = (float*)shmU + 256;
        redn[t] = np;
        redd[t] = dp;
        __syncthreads();
        for (int s2 = 128; s2 > 0; s2 >>= 1) {
            if (t < s2) { redn[t] += redn[t + s2]; redd[t] += redd[t + s2]; }
            __syncthreads();
        }
        if (t == 0) {
            atomicAdd(&scal[0], redn[0]);
            atomicAdd(&scal[1], redd[0]);
        }
    }
}

// ---------------- fused layer 2 (8 nodes/block, W2_rel staged in LDS) | finalize (r17 exact)
__global__ __launch_bounds__(512) void fused2_finalize_kernel(
    const float* __restrict__ h, const int2* __restrict__ srcw, const int* __restrict__ count,
    const float* __restrict__ w2t_rel, const float* __restrict__ w2t_root,
    const float* __restrict__ b2, float* __restrict__ out, const float* __restrict__ sspart,
    const float* __restrict__ scal) {
    __shared__ float wsrel[6400];
    __shared__ float a2[8][64], hrow[8][64];
    __shared__ float logits[8][104];
    __shared__ float b2s[104];
    int t = threadIdx.x;
    int b = blockIdx.x;
    if (b < NBLK_F2) {
        for (int i = t; i < 6400; i += 512) wsrel[i] = w2t_rel[i];
        if (t < NCLUST) b2s[t] = b2[t];
        int nn = t >> 6;
        int c = t & 63;
        int eslot = c >> 4;
        int q = c & 15;
        int n = b * 8 + nn;
        int len = count[n];
        const int2* bucket = srcw + n * CAP;
        float4 acc4 = make_float4(0.f, 0.f, 0.f, 0.f);
        for (int k = 0; k < len; k += 32) {
            int i0 = k + eslot,      i1 = k + 4 + eslot;
            int i2 = k + 8 + eslot,  i3 = k + 12 + eslot;
            int i4 = k + 16 + eslot, i5 = k + 20 + eslot;
            int i6 = k + 24 + eslot, i7 = k + 28 + eslot;
            int2 pa = bucket[i0]; int2 pb = bucket[i1];
            int2 pc = bucket[i2]; int2 pd = bucket[i3];
            int2 pe = bucket[i4]; int2 pf = bucket[i5];
            int2 pg = bucket[i6]; int2 ph = bucket[i7];
            if (i0 >= len) pa = make_int2(0, 0);
            if (i1 >= len) pb = make_int2(0, 0);
            if (i2 >= len) pc = make_int2(0, 0);
            if (i3 >= len) pd = make_int2(0, 0);
            if (i4 >= len) pe = make_int2(0, 0);
            if (i5 >= len) pf = make_int2(0, 0);
            if (i6 >= len) pg = make_int2(0, 0);
            if (i7 >= len) ph = make_int2(0, 0);
            float4 va = *(const float4*)(h + pa.x * 64 + q * 4);
            float4 vb = *(const float4*)(h + pb.x * 64 + q * 4);
            float4 vc = *(const float4*)(h + pc.x * 64 + q * 4);
            float4 vd = *(const float4*)(h + pd.x * 64 + q * 4);
            float4 ve = *(const float4*)(h + pe.x * 64 + q * 4);
            float4 vf = *(const float4*)(h + pf.x * 64 + q * 4);
            float4 vg = *(const float4*)(h + pg.x * 64 + q * 4);
            float4 vh = *(const float4*)(h + ph.x * 64 + q * 4);
            float wa = __int_as_float(pa.y), wb = __int_as_float(pb.y);
            float wc = __int_as_float(pc.y), wd = __int_as_float(pd.y);
            float we = __int_as_float(pe.y), wf = __int_as_float(pf.y);
            float wg = __int_as_float(pg.y), wh = __int_as_float(ph.y);
            acc4.x = fmaf(va.x, wa, acc4.x); acc4.y = fmaf(va.y, wa, acc4.y);
            acc4.z = fmaf(va.z, wa, acc4.z); acc4.w = fmaf(va.w, wa, acc4.w);
            acc4.x = fmaf(vb.x, wb, acc4.x); acc4.y = fmaf(vb.y, wb, acc4.y);
            acc4.z = fmaf(vb.z, wb, acc4.z); acc4.w = fmaf(vb.w, wb, acc4.w);
            acc4.x = fmaf(vc.x, wc, acc4.x); acc4.y = fmaf(vc.y, wc, acc4.y);
            acc4.z = fmaf(vc.z, wc, acc4.z); acc4.w = fmaf(vc.w, wc, acc4.w);
            acc4.x = fmaf(vd.x, wd, acc4.x); acc4.y = fmaf(vd.y, wd, acc4.y);
            acc4.z = fmaf(vd.z, wd, acc4.z); acc4.w = fmaf(vd.w, wd, acc4.w);
            acc4.x = fmaf(ve.x, we, acc4.x); acc4.y = fmaf(ve.y, we, acc4.y);
            acc4.z = fmaf(ve.z, we, acc4.z); acc4.w = fmaf(ve.w, we, acc4.w);
            acc4.x = fmaf(vf.x, wf, acc4.x); acc4.y = fmaf(vf.y, wf, acc4.y);
            acc4.z = fmaf(vf.z, wf, acc4.z); acc4.w = fmaf(vf.w, wf, acc4.w);
            acc4.x = fmaf(vg.x, wg, acc4.x); acc4.y = fmaf(vg.y, wg, acc4.y);
            acc4.z = fmaf(vg.z, wg, acc4.z); acc4.w = fmaf(vg.w, wg, acc4.w);
            acc4.x = fmaf(vh.x, wh, acc4.x); acc4.y = fmaf(vh.y, wh, acc4.y);
            acc4.z = fmaf(vh.z, wh, acc4.z); acc4.w = fmaf(vh.w, wh, acc4.w);
        }
        acc4.x += __shfl_xor(acc4.x, 16); acc4.y += __shfl_xor(acc4.y, 16);
        acc4.z += __shfl_xor(acc4.z, 16); acc4.w += __shfl_xor(acc4.w, 16);
        acc4.x += __shfl_xor(acc4.x, 32); acc4.y += __shfl_xor(acc4.y, 32);
        acc4.z += __shfl_xor(acc4.z, 32); acc4.w += __shfl_xor(acc4.w, 32);
        if (eslot == 0) *(float4*)(&a2[nn][q * 4]) = acc4;
        hrow[nn][c] = h[n * 64 + c];
        __syncthreads();
        int g = t >> 7, c2 = t & 127;
        if (c2 < NCLUST) {
            int na = 2 * g, nb2 = 2 * g + 1;
            float s0 = b2s[c2], s1 = s0;
#pragma unroll 8
            for (int kk = 0; kk < 64; ++kk) {
                float wr = wsrel[kk * 100 + c2];
                float wo = w2t_root[kk * 100 + c2];
                s0 = fmaf(a2[na][kk], wr, fmaf(hrow[na][kk], wo, s0));
                s1 = fmaf(a2[nb2][kk], wr, fmaf(hrow[nb2][kk], wo, s1));
            }
            logits[na][c2] = s0;
            logits[nb2][c2] = s1;
        }
        __syncthreads();
        float v0 = logits[nn][c];
        float v1 = (c < NCLUST - 64) ? logits[nn][64 + c] : -INFINITY;
        float m = fmaxf(v0, v1);
#pragma unroll
        for (int off = 32; off > 0; off >>= 1) m = fmaxf(m, __shfl_xor(m, off));
        float e0 = __expf(v0 - m);
        float e1 = (c < NCLUST - 64) ? __expf(v1 - m) : 0.f;
        float s = e0 + e1;
#pragma unroll
        for (int off = 32; off > 0; off >>= 1) s += __shfl_xor(s, off);
        float inv = 1.f / s;
        out[n * NCLUST + c] = e0 * inv;
        if (c < NCLUST - 64) out[n * NCLUST + 64 + c] = e1 * inv;
    } else {
        float* red = wsrel;
        float sv = 0.f;
        if (t < 256)
            for (int bb = 0; bb < NBLK_N; ++bb) sv += sspart[bb * 256 + t];
        red[t] = sv * sv;
        __syncthreads();
        for (int s = 256; s > 0; s >>= 1) {
            if (t < s) red[t] += red[t + s];
            __syncthreads();
        }
        float ssnorm = sqrtf(red[0]);
        __syncthreads();
        float diff = (t < 256) ? (sv / ssnorm - ((t % 17 == 0) ? 0.25f : 0.f)) : 0.f;
        red[t] = diff * diff;
        __syncthreads();
        for (int s = 256; s > 0; s >>= 1) {
            if (t < s) red[t] += red[t + s];
            __syncthreads();
        }
        if (t == 0) {
            out[N_NODES * NCLUST + 0] = -(scal[0] / scal[1]);
            out[N_NODES * NCLUST + 1] = sqrtf(red[0]);
        }
    }
}

extern "C" void kernel_launch(void* const* d_in, const int* in_sizes, int n_in,
                              void* d_out, int out_size, void* d_ws, size_t ws_size,
                              hipStream_t stream) {
    const float* x       = (const float*)d_in[0];
    const int*   ei      = (const int*)d_in[1];
    const float* ew      = (const float*)d_in[2];
    const float* W1_rel  = (const float*)d_in[3];
    const float* W1_root = (const float*)d_in[4];
    const float* b1      = (const float*)d_in[5];
    const float* W2_rel  = (const float*)d_in[6];
    const float* W2_root = (const float*)d_in[7];
    const float* b2      = (const float*)d_in[8];
    float* out = (float*)d_out;
    int*   wsi = (int*)d_ws;

    int*   bincnt  = wsi + OFF_BINCNT;
    float* scal    = (float*)(wsi + OFF_SCAL);
    int*   count   = wsi + OFF_COUNT;
    float* sspart  = (float*)(wsi + OFF_SSPART);
    float* norm2   = (float*)(wsi + OFF_NORM2);
    float* w2trel  = (float*)(wsi + OFF_W2TREL);
    float* w2troot = (float*)(wsi + OFF_W2TROOT);
    float* smc     = (float*)(wsi + OFF_SMC);
    float* h       = (float*)(wsi + OFF_H);
    int2*  srcw    = (int2*)(wsi + OFF_SRCW);
    int2*  binbuf  = (int2*)(wsi + OFF_BINBUF);

    hipMemsetAsync(wsi, 0, ZERO_ELEMS * sizeof(int), stream);
    binA_kernel<<<NBLK_E + NBLK_N + 2, 256, 0, stream>>>(x, ei, ew, smc, norm2, bincnt, binbuf,
                                                         W2_rel, W2_root, w2trel, w2troot);
    binBF1_kernel<<<NBIN + NBLK_N + NBLK_E, 256, 0, stream>>>(
        binbuf, bincnt, count, srcw, x, W1_rel, W1_root, b1, h,
        smc, sspart, ei, ew, norm2, scal);
    fused2_finalize_kernel<<<NBLK_F2 + 1, 512, 0, stream>>>(h, srcw, count, w2trel, w2troot,
                                                            b2, out, sspart, scal);
}

// Round 20
// 88.717 us; speedup vs baseline: 3.9997x; 1.0406x over previous
//
#include <hip/hip_runtime.h>
#include <math.h>

#define N_NODES 12000
#define F_INN 16
#define HIDD 64
#define NCLUST 100
#define NEDGE 384000
#define NBLK_N 47
#define CAP 96
#define LCAP 97            // LDS-only bucket stride (bank-conflict pad; srcw stays CAP)
#define EPT 4
#define NBLK_E 375
#define NBLK_F1 (N_NODES / 4)          // 3000
#define NBLK_F2 (N_NODES / 8)          // 1500
#define NBIN 188
#define BINW 64
#define BCAP 2560
#define STCAP 24

// ws layout (4-byte element offsets) — r17:
#define OFF_BINCNT  0        // 188 int (memset)
#define OFF_SCAL    188      // 2 f32   (memset)
#define ZERO_ELEMS  190
#define OFF_COUNT   192
#define OFF_SSPART  12192
#define OFF_NORM2   24224
#define OFF_W2TREL  36224
#define OFF_W2TROOT 42624
#define OFF_SMC     49024
#define OFF_H       241024
#define OFF_SRCW    1009024
#define OFF_BINBUF  3313024  // 188*2560 int2

// ---------------- pass A: edge binning | smc softmax+norm2 | W2 transpose (r17 exact)
__global__ void binA_kernel(const float* __restrict__ x, const int* __restrict__ ei,
                            const float* __restrict__ ew, float* __restrict__ smc,
                            float* __restrict__ norm2, int* __restrict__ bincnt,
                            int2* __restrict__ binbuf, const float* __restrict__ W2_rel,
                            const float* __restrict__ W2_root, float* __restrict__ w2t_rel,
                            float* __restrict__ w2t_root) {
    __shared__ int shmA[188 + 188 * STCAP * 2];
    int t = threadIdx.x;
    int b = blockIdx.x;
    if (b < NBLK_E) {
        int* scnt = shmA;
        int2* sbuf = (int2*)(shmA + 188);
        for (int i = t; i < 188; i += 256) scnt[i] = 0;
        __syncthreads();
        int tid = b * 256 + t;
        int e0 = tid * EPT;
        int4 sv = *(const int4*)(ei + e0);
        int4 dv = *(const int4*)(ei + NEDGE + e0);
        float4 wv = *(const float4*)(ew + e0);
        int s[EPT] = {sv.x, sv.y, sv.z, sv.w};
        int d[EPT] = {dv.x, dv.y, dv.z, dv.w};
        float w[EPT] = {wv.x, wv.y, wv.z, wv.w};
#pragma unroll
        for (int i = 0; i < EPT; ++i) {
            int bin = d[i] >> 6;
            int dl = d[i] & 63;
            int2 rec = make_int2(s[i] | (dl << 16), __float_as_int(w[i]));
            int pos = atomicAdd(&scnt[bin], 1);
            if (pos < STCAP) {
                sbuf[bin * STCAP + pos] = rec;
            } else {
                int base = atomicAdd(&bincnt[bin], 1);
                binbuf[bin * BCAP + base] = rec;
            }
        }
        __syncthreads();
        if (t < 188) {
            int k = scnt[t];
            if (k > STCAP) k = STCAP;
            if (k > 0) {
                int base = atomicAdd(&bincnt[t], k);
                for (int i = 0; i < k; ++i) binbuf[t * BCAP + base + i] = sbuf[t * STCAP + i];
            }
        }
    } else if (b < NBLK_E + NBLK_N) {
        int i = (b - NBLK_E) * 256 + t;
        if (i >= N_NODES) return;
        const float4* xr = (const float4*)(x + i * 16);
        float4 r0 = xr[0], r1 = xr[1], r2 = xr[2], r3 = xr[3];
        float v[16] = {r0.x, r0.y, r0.z, r0.w, r1.x, r1.y, r1.z, r1.w,
                       r2.x, r2.y, r2.z, r2.w, r3.x, r3.y, r3.z, r3.w};
        float m = v[0];
#pragma unroll
        for (int k = 1; k < 16; ++k) m = fmaxf(m, v[k]);
        float s = 0.f;
#pragma unroll
        for (int k = 0; k < 16; ++k) { v[k] = __expf(v[k] - m); s += v[k]; }
        float inv = 1.f / s;
        float n2 = 0.f;
#pragma unroll
        for (int k = 0; k < 16; ++k) { v[k] *= inv; n2 += v[k] * v[k]; }
        float4* so = (float4*)(smc + i * 16);
        so[0] = make_float4(v[0], v[1], v[2], v[3]);
        so[1] = make_float4(v[4], v[5], v[6], v[7]);
        so[2] = make_float4(v[8], v[9], v[10], v[11]);
        so[3] = make_float4(v[12], v[13], v[14], v[15]);
        norm2[i] = n2;
    } else {
        float* fl = (float*)shmA;
        const float* src = (b == NBLK_E + NBLK_N) ? W2_rel : W2_root;
        float* dst = (b == NBLK_E + NBLK_N) ? w2t_rel : w2t_root;
        for (int i = t; i < 6400; i += 256) fl[i] = src[i];
        __syncthreads();
        for (int j = t; j < 6400; j += 256) {
            int kk = j / 100, cl = j - kk * 100;
            dst[j] = fl[cl * 64 + kk];
        }
    }
}

// ---------------- pass B: per-bin LDS bucketize (padded stride) -> coalesced srcw/count
// | ss partials | mincut  (r17 + bank-conflict pad)
__global__ void binB_kernel(const int2* __restrict__ binbuf, const int* __restrict__ bincnt,
                            int* __restrict__ count, int2* __restrict__ srcw,
                            const float* __restrict__ smc, float* __restrict__ sspart,
                            const int* __restrict__ ei, const float* __restrict__ ew,
                            const float* __restrict__ norm2, float* __restrict__ scal) {
    __shared__ int shmB[64 + 64 * LCAP * 2];   // cnt[64] + lbuck[64][97] int2 (49.9 KB)
    int t = threadIdx.x;
    int b = blockIdx.x;
    if (b < NBIN) {
        int* cnt = shmB;
        int2* lbuck = (int2*)(shmB + 64);
        for (int i = t; i < 64; i += 256) cnt[i] = 0;
        __syncthreads();
        int nE = bincnt[b];
        const int2* bp = binbuf + b * BCAP;
        for (int i = t; i < nE; i += 256) {     // coalesced bin read, LDS-atomic bucketize
            int2 rec = bp[i];
            int src = rec.x & 0xFFFF;
            int dl = rec.x >> 16;
            int pos = atomicAdd(&cnt[dl], 1);
            if (pos < CAP) lbuck[dl * LCAP + pos] = make_int2(src, rec.y);
        }
        __syncthreads();
        int nbase = b * BINW;
        int nvalid = N_NODES - nbase;
        if (nvalid > BINW) nvalid = BINW;
        if (t < nvalid) count[nbase + t] = cnt[t];
        int lim = nvalid * CAP;
        int2* out = srcw + (size_t)nbase * CAP;
        for (int i = t; i < lim; i += 256) {    // coalesced write; remap padded LDS row
            int node = i / CAP, slot = i - node * CAP;
            out[i] = lbuck[node * LCAP + slot];
        }
    } else if (b < NBIN + NBLK_N) {
        int bb = b - NBIN;
        float* rows = (float*)shmB;            // 256*17
        int n = bb * 256 + t;
        float* rp = rows + t * 17;
        if (n < N_NODES) {
            const float4* sr = (const float4*)(smc + n * 16);
            float4 a0 = sr[0], a1 = sr[1], a2v = sr[2], a3 = sr[3];
            rp[0] = a0.x;  rp[1] = a0.y;  rp[2] = a0.z;  rp[3] = a0.w;
            rp[4] = a1.x;  rp[5] = a1.y;  rp[6] = a1.z;  rp[7] = a1.w;
            rp[8] = a2v.x; rp[9] = a2v.y; rp[10] = a2v.z; rp[11] = a2v.w;
            rp[12] = a3.x; rp[13] = a3.y; rp[14] = a3.z; rp[15] = a3.w;
        } else {
#pragma unroll
            for (int k = 0; k < 16; ++k) rp[k] = 0.f;
        }
        __syncthreads();
        int a = t & 15, bq = t >> 4;
        float accs = 0.f;
#pragma unroll 4
        for (int r = 0; r < 256; ++r)
            accs = fmaf(rows[r * 17 + a], rows[r * 17 + bq], accs);
        sspart[bb * 256 + t] = accs;
    } else {
        int tid = (b - NBIN - NBLK_N) * 256 + t;
        int e0 = tid * EPT;
        int4 sv = *(const int4*)(ei + e0);
        int4 dv = *(const int4*)(ei + NEDGE + e0);
        float4 wv = *(const float4*)(ew + e0);
        int s[EPT] = {sv.x, sv.y, sv.z, sv.w};
        int d[EPT] = {dv.x, dv.y, dv.z, dv.w};
        float w[EPT] = {wv.x, wv.y, wv.z, wv.w};
        float np = 0.f, dp = 0.f;
#pragma unroll
        for (int i = 0; i < EPT; ++i) {
            const float4* ps = (const float4*)(smc + s[i] * 16);
            const float4* pd = (const float4*)(smc + d[i] * 16);
            float4 s0 = ps[0], s1 = ps[1], s2 = ps[2], s3 = ps[3];
            float4 d0 = pd[0], d1 = pd[1], d2 = pd[2], d3 = pd[3];
            float dot = s0.x * d0.x + s0.y * d0.y + s0.z * d0.z + s0.w * d0.w +
                        s1.x * d1.x + s1.y * d1.y + s1.z * d1.z + s1.w * d1.w +
                        s2.x * d2.x + s2.y * d2.y + s2.z * d2.z + s2.w * d2.w +
                        s3.x * d3.x + s3.y * d3.y + s3.z * d3.z + s3.w * d3.w;
            np = fmaf(w[i], dot, np);
            dp = fmaf(w[i], norm2[s[i]], dp);
        }
        float* redn = (float*)shmB;
        float* redd = (float*)shmB + 256;
        redn[t] = np;
        redd[t] = dp;
        __syncthreads();
        for (int s2 = 128; s2 > 0; s2 >>= 1) {
            if (t < s2) { redn[t] += redn[t + s2]; redd[t] += redd[t + s2]; }
            __syncthreads();
        }
        if (t == 0) {
            atomicAdd(&scal[0], redn[0]);
            atomicAdd(&scal[1], redd[0]);
        }
    }
}

// ---------------- fused layer 1 (pure) — r17 exact
__global__ void fused1_kernel(const float* __restrict__ x, const int2* __restrict__ srcw,
                              const int* __restrict__ count, const float* __restrict__ W1_rel,
                              const float* __restrict__ W1_root, const float* __restrict__ b1,
                              float* __restrict__ h) {
    __shared__ float shm[2304];
    int t = threadIdx.x;
    int b = blockIdx.x;
    float* wrelT  = shm;
    float* wrootT = shm + 1024;
    float* b1s    = shm + 2048;
    float* aggr   = shm + 2112;
    float* xs     = shm + 2176;
    for (int idx = t; idx < 1024; idx += 256) {
        int f = idx >> 4, k = idx & 15;
        wrelT[(k << 6) + f]  = W1_rel[idx];
        wrootT[(k << 6) + f] = W1_root[idx];
    }
    if (t < 64) b1s[t] = b1[t];
    int w = t >> 6, lane = t & 63;
    int j2 = lane >> 2;
    int q  = lane & 3;
    int n = b * 4 + w;
    int len = count[n];
    const int2* bucket = srcw + n * CAP;
    float4 acc4 = make_float4(0.f, 0.f, 0.f, 0.f);
    for (int k = 0; k < len; k += 32) {
        int ia = k + j2, ib = k + 16 + j2;
        int2 pa = bucket[ia];
        int2 pb = bucket[ib];
        if (ia >= len) pa = make_int2(0, 0);
        if (ib >= len) pb = make_int2(0, 0);
        float4 va = *(const float4*)(x + pa.x * 16 + q * 4);
        float4 vb = *(const float4*)(x + pb.x * 16 + q * 4);
        float wa = __int_as_float(pa.y), wb = __int_as_float(pb.y);
        acc4.x = fmaf(va.x, wa, acc4.x); acc4.y = fmaf(va.y, wa, acc4.y);
        acc4.z = fmaf(va.z, wa, acc4.z); acc4.w = fmaf(va.w, wa, acc4.w);
        acc4.x = fmaf(vb.x, wb, acc4.x); acc4.y = fmaf(vb.y, wb, acc4.y);
        acc4.z = fmaf(vb.z, wb, acc4.z); acc4.w = fmaf(vb.w, wb, acc4.w);
    }
    acc4.x += __shfl_xor(acc4.x, 4);  acc4.y += __shfl_xor(acc4.y, 4);
    acc4.z += __shfl_xor(acc4.z, 4);  acc4.w += __shfl_xor(acc4.w, 4);
    acc4.x += __shfl_xor(acc4.x, 8);  acc4.y += __shfl_xor(acc4.y, 8);
    acc4.z += __shfl_xor(acc4.z, 8);  acc4.w += __shfl_xor(acc4.w, 8);
    acc4.x += __shfl_xor(acc4.x, 16); acc4.y += __shfl_xor(acc4.y, 16);
    acc4.z += __shfl_xor(acc4.z, 16); acc4.w += __shfl_xor(acc4.w, 16);
    acc4.x += __shfl_xor(acc4.x, 32); acc4.y += __shfl_xor(acc4.y, 32);
    acc4.z += __shfl_xor(acc4.z, 32); acc4.w += __shfl_xor(acc4.w, 32);
    if (j2 == 0) *(float4*)(aggr + w * 16 + q * 4) = acc4;
    if (lane < 16) xs[w * 16 + lane] = x[n * 16 + lane];
    __syncthreads();
    float o = b1s[lane];
#pragma unroll
    for (int kk = 0; kk < 16; ++kk)
        o = fmaf(aggr[w * 16 + kk], wrelT[(kk << 6) + lane],
                 fmaf(xs[w * 16 + kk], wrootT[(kk << 6) + lane], o));
    h[n * 64 + lane] = fmaxf(o, 0.f);
}

// ---------------- fused layer 2 (8 nodes/block, W2_rel staged in LDS) | finalize (r17 exact)
__global__ __launch_bounds__(512) void fused2_finalize_kernel(
    const float* __restrict__ h, const int2* __restrict__ srcw, const int* __restrict__ count,
    const float* __restrict__ w2t_rel, const float* __restrict__ w2t_root,
    const float* __restrict__ b2, float* __restrict__ out, const float* __restrict__ sspart,
    const float* __restrict__ scal) {
    __shared__ float wsrel[6400];
    __shared__ float a2[8][64], hrow[8][64];
    __shared__ float logits[8][104];
    __shared__ float b2s[104];
    int t = threadIdx.x;
    int b = blockIdx.x;
    if (b < NBLK_F2) {
        for (int i = t; i < 6400; i += 512) wsrel[i] = w2t_rel[i];
        if (t < NCLUST) b2s[t] = b2[t];
        int nn = t >> 6;
        int c = t & 63;
        int eslot = c >> 4;
        int q = c & 15;
        int n = b * 8 + nn;
        int len = count[n];
        const int2* bucket = srcw + n * CAP;
        float4 acc4 = make_float4(0.f, 0.f, 0.f, 0.f);
        for (int k = 0; k < len; k += 32) {
            int i0 = k + eslot,      i1 = k + 4 + eslot;
            int i2 = k + 8 + eslot,  i3 = k + 12 + eslot;
            int i4 = k + 16 + eslot, i5 = k + 20 + eslot;
            int i6 = k + 24 + eslot, i7 = k + 28 + eslot;
            int2 pa = bucket[i0]; int2 pb = bucket[i1];
            int2 pc = bucket[i2]; int2 pd = bucket[i3];
            int2 pe = bucket[i4]; int2 pf = bucket[i5];
            int2 pg = bucket[i6]; int2 ph = bucket[i7];
            if (i0 >= len) pa = make_int2(0, 0);
            if (i1 >= len) pb = make_int2(0, 0);
            if (i2 >= len) pc = make_int2(0, 0);
            if (i3 >= len) pd = make_int2(0, 0);
            if (i4 >= len) pe = make_int2(0, 0);
            if (i5 >= len) pf = make_int2(0, 0);
            if (i6 >= len) pg = make_int2(0, 0);
            if (i7 >= len) ph = make_int2(0, 0);
            float4 va = *(const float4*)(h + pa.x * 64 + q * 4);
            float4 vb = *(const float4*)(h + pb.x * 64 + q * 4);
            float4 vc = *(const float4*)(h + pc.x * 64 + q * 4);
            float4 vd = *(const float4*)(h + pd.x * 64 + q * 4);
            float4 ve = *(const float4*)(h + pe.x * 64 + q * 4);
            float4 vf = *(const float4*)(h + pf.x * 64 + q * 4);
            float4 vg = *(const float4*)(h + pg.x * 64 + q * 4);
            float4 vh = *(const float4*)(h + ph.x * 64 + q * 4);
            float wa = __int_as_float(pa.y), wb = __int_as_float(pb.y);
            float wc = __int_as_float(pc.y), wd = __int_as_float(pd.y);
            float we = __int_as_float(pe.y), wf = __int_as_float(pf.y);
            float wg = __int_as_float(pg.y), wh = __int_as_float(ph.y);
            acc4.x = fmaf(va.x, wa, acc4.x); acc4.y = fmaf(va.y, wa, acc4.y);
            acc4.z = fmaf(va.z, wa, acc4.z); acc4.w = fmaf(va.w, wa, acc4.w);
            acc4.x = fmaf(vb.x, wb, acc4.x); acc4.y = fmaf(vb.y, wb, acc4.y);
            acc4.z = fmaf(vb.z, wb, acc4.z); acc4.w = fmaf(vb.w, wb, acc4.w);
            acc4.x = fmaf(vc.x, wc, acc4.x); acc4.y = fmaf(vc.y, wc, acc4.y);
            acc4.z = fmaf(vc.z, wc, acc4.z); acc4.w = fmaf(vc.w, wc, acc4.w);
            acc4.x = fmaf(vd.x, wd, acc4.x); acc4.y = fmaf(vd.y, wd, acc4.y);
            acc4.z = fmaf(vd.z, wd, acc4.z); acc4.w = fmaf(vd.w, wd, acc4.w);
            acc4.x = fmaf(ve.x, we, acc4.x); acc4.y = fmaf(ve.y, we, acc4.y);
            acc4.z = fmaf(ve.z, we, acc4.z); acc4.w = fmaf(ve.w, we, acc4.w);
            acc4.x = fmaf(vf.x, wf, acc4.x); acc4.y = fmaf(vf.y, wf, acc4.y);
            acc4.z = fmaf(vf.z, wf, acc4.z); acc4.w = fmaf(vf.w, wf, acc4.w);
            acc4.x = fmaf(vg.x, wg, acc4.x); acc4.y = fmaf(vg.y, wg, acc4.y);
            acc4.z = fmaf(vg.z, wg, acc4.z); acc4.w = fmaf(vg.w, wg, acc4.w);
            acc4.x = fmaf(vh.x, wh, acc4.x); acc4.y = fmaf(vh.y, wh, acc4.y);
            acc4.z = fmaf(vh.z, wh, acc4.z); acc4.w = fmaf(vh.w, wh, acc4.w);
        }
        acc4.x += __shfl_xor(acc4.x, 16); acc4.y += __shfl_xor(acc4.y, 16);
        acc4.z += __shfl_xor(acc4.z, 16); acc4.w += __shfl_xor(acc4.w, 16);
        acc4.x += __shfl_xor(acc4.x, 32); acc4.y += __shfl_xor(acc4.y, 32);
        acc4.z += __shfl_xor(acc4.z, 32); acc4.w += __shfl_xor(acc4.w, 32);
        if (eslot == 0) *(float4*)(&a2[nn][q * 4]) = acc4;
        hrow[nn][c] = h[n * 64 + c];
        __syncthreads();
        int g = t >> 7, c2 = t & 127;
        if (c2 < NCLUST) {
            int na = 2 * g, nb2 = 2 * g + 1;
            float s0 = b2s[c2], s1 = s0;
#pragma unroll 8
            for (int kk = 0; kk < 64; ++kk) {
                float wr = wsrel[kk * 100 + c2];
                float wo = w2t_root[kk * 100 + c2];
                s0 = fmaf(a2[na][kk], wr, fmaf(hrow[na][kk], wo, s0));
                s1 = fmaf(a2[nb2][kk], wr, fmaf(hrow[nb2][kk], wo, s1));
            }
            logits[na][c2] = s0;
            logits[nb2][c2] = s1;
        }
        __syncthreads();
        float v0 = logits[nn][c];
        float v1 = (c < NCLUST - 64) ? logits[nn][64 + c] : -INFINITY;
        float m = fmaxf(v0, v1);
#pragma unroll
        for (int off = 32; off > 0; off >>= 1) m = fmaxf(m, __shfl_xor(m, off));
        float e0 = __expf(v0 - m);
        float e1 = (c < NCLUST - 64) ? __expf(v1 - m) : 0.f;
        float s = e0 + e1;
#pragma unroll
        for (int off = 32; off > 0; off >>= 1) s += __shfl_xor(s, off);
        float inv = 1.f / s;
        out[n * NCLUST + c] = e0 * inv;
        if (c < NCLUST - 64) out[n * NCLUST + 64 + c] = e1 * inv;
    } else {
        float* red = wsrel;
        float sv = 0.f;
        if (t < 256)
            for (int bb = 0; bb < NBLK_N; ++bb) sv += sspart[bb * 256 + t];
        red[t] = sv * sv;
        __syncthreads();
        for (int s = 256; s > 0; s >>= 1) {
            if (t < s) red[t] += red[t + s];
            __syncthreads();
        }
        float ssnorm = sqrtf(red[0]);
        __syncthreads();
        float diff = (t < 256) ? (sv / ssnorm - ((t % 17 == 0) ? 0.25f : 0.f)) : 0.f;
        red[t] = diff * diff;
        __syncthreads();
        for (int s = 256; s > 0; s >>= 1) {
            if (t < s) red[t] += red[t + s];
            __syncthreads();
        }
        if (t == 0) {
            out[N_NODES * NCLUST + 0] = -(scal[0] / scal[1]);
            out[N_NODES * NCLUST + 1] = sqrtf(red[0]);
        }
    }
}

extern "C" void kernel_launch(void* const* d_in, const int* in_sizes, int n_in,
                              void* d_out, int out_size, void* d_ws, size_t ws_size,
                              hipStream_t stream) {
    const float* x       = (const float*)d_in[0];
    const int*   ei      = (const int*)d_in[1];
    const float* ew      = (const float*)d_in[2];
    const float* W1_rel  = (const float*)d_in[3];
    const float* W1_root = (const float*)d_in[4];
    const float* b1      = (const float*)d_in[5];
    const float* W2_rel  = (const float*)d_in[6];
    const float* W2_root = (const float*)d_in[7];
    const float* b2      = (const float*)d_in[8];
    float* out = (float*)d_out;
    int*   wsi = (int*)d_ws;

    int*   bincnt  = wsi + OFF_BINCNT;
    float* scal    = (float*)(wsi + OFF_SCAL);
    int*   count   = wsi + OFF_COUNT;
    float* sspart  = (float*)(wsi + OFF_SSPART);
    float* norm2   = (float*)(wsi + OFF_NORM2);
    float* w2trel  = (float*)(wsi + OFF_W2TREL);
    float* w2troot = (float*)(wsi + OFF_W2TROOT);
    float* smc     = (float*)(wsi + OFF_SMC);
    float* h       = (float*)(wsi + OFF_H);
    int2*  srcw    = (int2*)(wsi + OFF_SRCW);
    int2*  binbuf  = (int2*)(wsi + OFF_BINBUF);

    hipMemsetAsync(wsi, 0, ZERO_ELEMS * sizeof(int), stream);
    binA_kernel<<<NBLK_E + NBLK_N + 2, 256, 0, stream>>>(x, ei, ew, smc, norm2, bincnt, binbuf,
                                                         W2_rel, W2_root, w2trel, w2troot);
    binB_kernel<<<NBIN + NBLK_N + NBLK_E, 256, 0, stream>>>(binbuf, bincnt, count, srcw,
                                                            smc, sspart, ei, ew, norm2, scal);
    fused1_kernel<<<NBLK_F1, 256, 0, stream>>>(x, srcw, count, W1_rel, W1_root, b1, h);
    fused2_finalize_kernel<<<NBLK_F2 + 1, 512, 0, stream>>>(h, srcw, count, w2trel, w2troot,
                                                            b2, out, sspart, scal);
}

// Round 21
// 88.298 us; speedup vs baseline: 4.0187x; 1.0047x over previous
//
#include <hip/hip_runtime.h>
#include <math.h>

#define N_NODES 12000
#define F_INN 16
#define HIDD 64
#define NCLUST 100
#define NEDGE 384000
#define NBLK_N 47
#define CAP 96
#define LCAP 97            // padded LDS bucket stride (bank-conflict fix, r20-proven)
#define EPT 4
#define NBLK_E 375
#define NBLK_F1 (N_NODES / 8)          // 1500 (8 nodes/block, 512 thr)
#define NBLK_ME 188                    // mincut blocks at 512 thr, EPT 4 (guarded)
#define NBLK_F2 (N_NODES / 8)          // 1500
#define NBIN 188
#define BINW 64
#define BCAP 2560
#define STCAP 24

// ws layout (4-byte element offsets):
#define OFF_BINCNT  0        // 188 int (memset)
#define OFF_SCAL    188      // 2 f32   (memset)
#define ZERO_ELEMS  190
#define OFF_SSPART  192      // 12032 f32
#define OFF_NORM2   12224    // 12000 f32
#define OFF_W2TREL  24224    // 6400 f32
#define OFF_W2TROOT 30624    // 6400 f32
#define OFF_SMC     37024    // 192000 f32
#define OFF_H       229024   // 768000 f32
#define OFF_BINBUF  997024   // 188*2560 int2 (byte 3988096, 8B aligned)

// ---------------- pass A: edge binning | smc softmax+norm2 | W2 transpose (r17/r20 exact)
__global__ void binA_kernel(const float* __restrict__ x, const int* __restrict__ ei,
                            const float* __restrict__ ew, float* __restrict__ smc,
                            float* __restrict__ norm2, int* __restrict__ bincnt,
                            int2* __restrict__ binbuf, const float* __restrict__ W2_rel,
                            const float* __restrict__ W2_root, float* __restrict__ w2t_rel,
                            float* __restrict__ w2t_root) {
    __shared__ int shmA[188 + 188 * STCAP * 2];
    int t = threadIdx.x;
    int b = blockIdx.x;
    if (b < NBLK_E) {
        int* scnt = shmA;
        int2* sbuf = (int2*)(shmA + 188);
        for (int i = t; i < 188; i += 256) scnt[i] = 0;
        __syncthreads();
        int tid = b * 256 + t;
        int e0 = tid * EPT;
        int4 sv = *(const int4*)(ei + e0);
        int4 dv = *(const int4*)(ei + NEDGE + e0);
        float4 wv = *(const float4*)(ew + e0);
        int s[EPT] = {sv.x, sv.y, sv.z, sv.w};
        int d[EPT] = {dv.x, dv.y, dv.z, dv.w};
        float w[EPT] = {wv.x, wv.y, wv.z, wv.w};
#pragma unroll
        for (int i = 0; i < EPT; ++i) {
            int bin = d[i] >> 6;
            int dl = d[i] & 63;
            int2 rec = make_int2(s[i] | (dl << 16), __float_as_int(w[i]));
            int pos = atomicAdd(&scnt[bin], 1);
            if (pos < STCAP) {
                sbuf[bin * STCAP + pos] = rec;
            } else {
                int base = atomicAdd(&bincnt[bin], 1);
                binbuf[bin * BCAP + base] = rec;
            }
        }
        __syncthreads();
        if (t < 188) {
            int k = scnt[t];
            if (k > STCAP) k = STCAP;
            if (k > 0) {
                int base = atomicAdd(&bincnt[t], k);
                for (int i = 0; i < k; ++i) binbuf[t * BCAP + base + i] = sbuf[t * STCAP + i];
            }
        }
    } else if (b < NBLK_E + NBLK_N) {
        int i = (b - NBLK_E) * 256 + t;
        if (i >= N_NODES) return;
        const float4* xr = (const float4*)(x + i * 16);
        float4 r0 = xr[0], r1 = xr[1], r2 = xr[2], r3 = xr[3];
        float v[16] = {r0.x, r0.y, r0.z, r0.w, r1.x, r1.y, r1.z, r1.w,
                       r2.x, r2.y, r2.z, r2.w, r3.x, r3.y, r3.z, r3.w};
        float m = v[0];
#pragma unroll
        for (int k = 1; k < 16; ++k) m = fmaxf(m, v[k]);
        float s = 0.f;
#pragma unroll
        for (int k = 0; k < 16; ++k) { v[k] = __expf(v[k] - m); s += v[k]; }
        float inv = 1.f / s;
        float n2 = 0.f;
#pragma unroll
        for (int k = 0; k < 16; ++k) { v[k] *= inv; n2 += v[k] * v[k]; }
        float4* so = (float4*)(smc + i * 16);
        so[0] = make_float4(v[0], v[1], v[2], v[3]);
        so[1] = make_float4(v[4], v[5], v[6], v[7]);
        so[2] = make_float4(v[8], v[9], v[10], v[11]);
        so[3] = make_float4(v[12], v[13], v[14], v[15]);
        norm2[i] = n2;
    } else {
        float* fl = (float*)shmA;
        const float* src = (b == NBLK_E + NBLK_N) ? W2_rel : W2_root;
        float* dst = (b == NBLK_E + NBLK_N) ? w2t_rel : w2t_root;
        for (int i = t; i < 6400; i += 256) fl[i] = src[i];
        __syncthreads();
        for (int j = t; j < 6400; j += 256) {
            int kk = j / 100, cl = j - kk * 100;
            dst[j] = fl[cl * 64 + kk];
        }
    }
}

// ---------------- fused1 direct-from-bins: per-block scan+filter+LDS-bucketize (8 nodes)
// + wave-per-node gather from LDS + F1 GEMV | ss partials | mincut  (no srcw/count!)
__global__ __launch_bounds__(512) void fused1_kernel(
    const int2* __restrict__ binbuf, const int* __restrict__ bincnt,
    const float* __restrict__ x, const float* __restrict__ W1_rel,
    const float* __restrict__ W1_root, const float* __restrict__ b1, float* __restrict__ h,
    const float* __restrict__ smc, float* __restrict__ sspart, const int* __restrict__ ei,
    const float* __restrict__ ew, const float* __restrict__ norm2, float* __restrict__ scal) {
    __shared__ int lb[8 * LCAP * 2 + 8];   // lbuck[8][97] int2 + cnt[8]  (6.2 KB)
    __shared__ float wrelT[1024], wrootT[1024], b1s[64];   // 8.5 KB
    __shared__ float shm[4352];            // ss rows / mincut red  (17.4 KB)
    int t = threadIdx.x;
    int b = blockIdx.x;
    if (b < NBLK_F1) {
        int2* lbuck = (int2*)lb;
        int* cnt = lb + 8 * LCAP * 2;
        for (int idx = t; idx < 1024; idx += 512) {
            int f = idx >> 4, k = idx & 15;
            wrelT[(k << 6) + f]  = W1_rel[idx];
            wrootT[(k << 6) + f] = W1_root[idx];
        }
        if (t < 64) b1s[t] = b1[t];
        if (t < 8) cnt[t] = 0;
        __syncthreads();
        int bin = b >> 3;              // 8 blocks per bin
        int sub = b & 7;               // this block's 8-node slice: dl in [sub*8, sub*8+8)
        int nE = bincnt[bin];
        const int2* bp = binbuf + bin * BCAP;
        for (int i = t; i < nE; i += 512) {
            int2 rec = bp[i];
            int dl = rec.x >> 16;
            if ((dl >> 3) == sub) {
                int ln = dl & 7;
                int pos = atomicAdd(&cnt[ln], 1);
                if (pos < CAP) lbuck[ln * LCAP + pos] = make_int2(rec.x & 0xFFFF, rec.y);
            }
        }
        __syncthreads();
        // wave-per-node gather from LDS (r17 predicated batches) + F1 epilogue (r19-verified)
        int w = t >> 6, lane = t & 63;
        int j2 = lane >> 2;   // edge slot 0..15
        int q  = lane & 3;    // float4 chunk of the 16-float x row
        int n = b * 8 + w;
        int len = cnt[w];
        const int2* bucket = lbuck + w * LCAP;
        float4 acc4 = make_float4(0.f, 0.f, 0.f, 0.f);
        for (int k = 0; k < len; k += 32) {
            int ia = k + j2, ib = k + 16 + j2;
            int2 pa = bucket[ia];
            int2 pb = bucket[ib];
            if (ia >= len) pa = make_int2(0, 0);   // w=0 -> fma identity
            if (ib >= len) pb = make_int2(0, 0);
            float4 va = *(const float4*)(x + pa.x * 16 + q * 4);
            float4 vb = *(const float4*)(x + pb.x * 16 + q * 4);
            float wa = __int_as_float(pa.y), wb = __int_as_float(pb.y);
            acc4.x = fmaf(va.x, wa, acc4.x); acc4.y = fmaf(va.y, wa, acc4.y);
            acc4.z = fmaf(va.z, wa, acc4.z); acc4.w = fmaf(va.w, wa, acc4.w);
            acc4.x = fmaf(vb.x, wb, acc4.x); acc4.y = fmaf(vb.y, wb, acc4.y);
            acc4.z = fmaf(vb.z, wb, acc4.z); acc4.w = fmaf(vb.w, wb, acc4.w);
        }
        acc4.x += __shfl_xor(acc4.x, 4);  acc4.y += __shfl_xor(acc4.y, 4);
        acc4.z += __shfl_xor(acc4.z, 4);  acc4.w += __shfl_xor(acc4.w, 4);
        acc4.x += __shfl_xor(acc4.x, 8);  acc4.y += __shfl_xor(acc4.y, 8);
        acc4.z += __shfl_xor(acc4.z, 8);  acc4.w += __shfl_xor(acc4.w, 8);
        acc4.x += __shfl_xor(acc4.x, 16); acc4.y += __shfl_xor(acc4.y, 16);
        acc4.z += __shfl_xor(acc4.z, 16); acc4.w += __shfl_xor(acc4.w, 16);
        acc4.x += __shfl_xor(acc4.x, 32); acc4.y += __shfl_xor(acc4.y, 32);
        acc4.z += __shfl_xor(acc4.z, 32); acc4.w += __shfl_xor(acc4.w, 32);
        // aggr[kk] == component (kk&3) of acc4 on lane (kk>>2)
        float xv = (lane < 16) ? x[n * 16 + lane] : 0.f;
        float o = b1s[lane];
#define F1STEP(KK, COMP) { float ag = __shfl(acc4.COMP, (KK) >> 2);            \
                           float xb = __shfl(xv, (KK));                        \
                           o = fmaf(ag, wrelT[((KK) << 6) + lane],             \
                                    fmaf(xb, wrootT[((KK) << 6) + lane], o)); }
        F1STEP(0, x)  F1STEP(1, y)  F1STEP(2, z)  F1STEP(3, w)
        F1STEP(4, x)  F1STEP(5, y)  F1STEP(6, z)  F1STEP(7, w)
        F1STEP(8, x)  F1STEP(9, y)  F1STEP(10, z) F1STEP(11, w)
        F1STEP(12, x) F1STEP(13, y) F1STEP(14, z) F1STEP(15, w)
#undef F1STEP
        h[n * 64 + lane] = fmaxf(o, 0.f);
    } else if (b < NBLK_F1 + NBLK_N) {
        // ---- ss partials (S^T S) — 512 thr, entries in t<256 (r8-proven)
        int bb = b - NBLK_F1;
        float* rows = shm;            // 256*17
        int n = bb * 256 + t;
        if (t < 256) {
            float* rp = rows + t * 17;
            if (n < N_NODES) {
                const float4* sr = (const float4*)(smc + n * 16);
                float4 a0 = sr[0], a1 = sr[1], a2v = sr[2], a3 = sr[3];
                rp[0] = a0.x;  rp[1] = a0.y;  rp[2] = a0.z;  rp[3] = a0.w;
                rp[4] = a1.x;  rp[5] = a1.y;  rp[6] = a1.z;  rp[7] = a1.w;
                rp[8] = a2v.x; rp[9] = a2v.y; rp[10] = a2v.z; rp[11] = a2v.w;
                rp[12] = a3.x; rp[13] = a3.y; rp[14] = a3.z; rp[15] = a3.w;
            } else {
#pragma unroll
                for (int k = 0; k < 16; ++k) rp[k] = 0.f;
            }
        }
        __syncthreads();
        if (t < 256) {
            int a = t & 15, bq = t >> 4;
            float accs = 0.f;
#pragma unroll 4
            for (int r = 0; r < 256; ++r)
                accs = fmaf(rows[r * 17 + a], rows[r * 17 + bq], accs);
            sspart[bb * 256 + t] = accs;
        }
    } else {
        // ---- mincut num/den edge reduction — 512 thr, EPT 4, guarded (r8-proven)
        int tid = (b - NBLK_F1 - NBLK_N) * 512 + t;
        int e0 = tid * EPT;
        float np = 0.f, dp = 0.f;
        if (e0 < NEDGE) {
            int4 sv = *(const int4*)(ei + e0);
            int4 dv = *(const int4*)(ei + NEDGE + e0);
            float4 wv = *(const float4*)(ew + e0);
            int s[EPT] = {sv.x, sv.y, sv.z, sv.w};
            int d[EPT] = {dv.x, dv.y, dv.z, dv.w};
            float w[EPT] = {wv.x, wv.y, wv.z, wv.w};
#pragma unroll
            for (int i = 0; i < EPT; ++i) {
                const float4* ps = (const float4*)(smc + s[i] * 16);
                const float4* pd = (const float4*)(smc + d[i] * 16);
                float4 s0 = ps[0], s1 = ps[1], s2 = ps[2], s3 = ps[3];
                float4 d0 = pd[0], d1 = pd[1], d2 = pd[2], d3 = pd[3];
                float dot = s0.x * d0.x + s0.y * d0.y + s0.z * d0.z + s0.w * d0.w +
                            s1.x * d1.x + s1.y * d1.y + s1.z * d1.z + s1.w * d1.w +
                            s2.x * d2.x + s2.y * d2.y + s2.z * d2.z + s2.w * d2.w +
                            s3.x * d3.x + s3.y * d3.y + s3.z * d3.z + s3.w * d3.w;
                np = fmaf(w[i], dot, np);
                dp = fmaf(w[i], norm2[s[i]], dp);
            }
        }
        float* redn = shm;
        float* redd = shm + 512;
        redn[t] = np;
        redd[t] = dp;
        __syncthreads();
        for (int s2 = 256; s2 > 0; s2 >>= 1) {
            if (t < s2) { redn[t] += redn[t + s2]; redd[t] += redd[t + s2]; }
            __syncthreads();
        }
        if (t == 0) {
            atomicAdd(&scal[0], redn[0]);
            atomicAdd(&scal[1], redd[0]);
        }
    }
}

// ---------------- fused2 direct-from-bins: per-block scan+filter+LDS-bucketize (8 nodes)
// + r17 gather (buckets in LDS) + GEMV + softmax | finalize
__global__ __launch_bounds__(512) void fused2_finalize_kernel(
    const int2* __restrict__ binbuf, const int* __restrict__ bincnt,
    const float* __restrict__ h, const float* __restrict__ w2t_rel,
    const float* __restrict__ w2t_root, const float* __restrict__ b2, float* __restrict__ out,
    const float* __restrict__ sspart, const float* __restrict__ scal) {
    __shared__ float wsrel[6400];      // 25.6 KB; finalize reuses as red
    __shared__ int lb[8 * LCAP * 2 + 8];   // lbuck[8][97] int2 + cnt[8]  (6.2 KB)
    __shared__ float a2[8][64], hrow[8][64];
    __shared__ float logits[8][104];
    __shared__ float b2s[104];
    int t = threadIdx.x;
    int b = blockIdx.x;
    if (b < NBLK_F2) {
        int2* lbuck = (int2*)lb;
        int* cnt = lb + 8 * LCAP * 2;
        for (int i = t; i < 6400; i += 512) wsrel[i] = w2t_rel[i];
        if (t < NCLUST) b2s[t] = b2[t];
        if (t < 8) cnt[t] = 0;
        __syncthreads();
        int bin = b >> 3;
        int sub = b & 7;
        int nE = bincnt[bin];
        const int2* bp = binbuf + bin * BCAP;
        for (int i = t; i < nE; i += 512) {
            int2 rec = bp[i];
            int dl = rec.x >> 16;
            if ((dl >> 3) == sub) {
                int ln = dl & 7;
                int pos = atomicAdd(&cnt[ln], 1);
                if (pos < CAP) lbuck[ln * LCAP + pos] = make_int2(rec.x & 0xFFFF, rec.y);
            }
        }
        __syncthreads();
        int nn = t >> 6;            // wave id = node slot 0..7
        int c = t & 63;
        int eslot = c >> 4;         // edge slot 0..3
        int q = c & 15;             // float4 chunk of the 64-float h row
        int n = b * 8 + nn;
        int len = cnt[nn];
        const int2* bucket = lbuck + nn * LCAP;
        float4 acc4 = make_float4(0.f, 0.f, 0.f, 0.f);
        for (int k = 0; k < len; k += 32) {   // predicated full-width batches (r17 order)
            int i0 = k + eslot,      i1 = k + 4 + eslot;
            int i2 = k + 8 + eslot,  i3 = k + 12 + eslot;
            int i4 = k + 16 + eslot, i5 = k + 20 + eslot;
            int i6 = k + 24 + eslot, i7 = k + 28 + eslot;
            int2 pa = bucket[i0]; int2 pb = bucket[i1];
            int2 pc = bucket[i2]; int2 pd = bucket[i3];
            int2 pe = bucket[i4]; int2 pf = bucket[i5];
            int2 pg = bucket[i6]; int2 ph = bucket[i7];
            if (i0 >= len) pa = make_int2(0, 0);
            if (i1 >= len) pb = make_int2(0, 0);
            if (i2 >= len) pc = make_int2(0, 0);
            if (i3 >= len) pd = make_int2(0, 0);
            if (i4 >= len) pe = make_int2(0, 0);
            if (i5 >= len) pf = make_int2(0, 0);
            if (i6 >= len) pg = make_int2(0, 0);
            if (i7 >= len) ph = make_int2(0, 0);
            float4 va = *(const float4*)(h + pa.x * 64 + q * 4);
            float4 vb = *(const float4*)(h + pb.x * 64 + q * 4);
            float4 vc = *(const float4*)(h + pc.x * 64 + q * 4);
            float4 vd = *(const float4*)(h + pd.x * 64 + q * 4);
            float4 ve = *(const float4*)(h + pe.x * 64 + q * 4);
            float4 vf = *(const float4*)(h + pf.x * 64 + q * 4);
            float4 vg = *(const float4*)(h + pg.x * 64 + q * 4);
            float4 vh = *(const float4*)(h + ph.x * 64 + q * 4);
            float wa = __int_as_float(pa.y), wb = __int_as_float(pb.y);
            float wc = __int_as_float(pc.y), wd = __int_as_float(pd.y);
            float we = __int_as_float(pe.y), wf = __int_as_float(pf.y);
            float wg = __int_as_float(pg.y), wh = __int_as_float(ph.y);
            acc4.x = fmaf(va.x, wa, acc4.x); acc4.y = fmaf(va.y, wa, acc4.y);
            acc4.z = fmaf(va.z, wa, acc4.z); acc4.w = fmaf(va.w, wa, acc4.w);
            acc4.x = fmaf(vb.x, wb, acc4.x); acc4.y = fmaf(vb.y, wb, acc4.y);
            acc4.z = fmaf(vb.z, wb, acc4.z); acc4.w = fmaf(vb.w, wb, acc4.w);
            acc4.x = fmaf(vc.x, wc, acc4.x); acc4.y = fmaf(vc.y, wc, acc4.y);
            acc4.z = fmaf(vc.z, wc, acc4.z); acc4.w = fmaf(vc.w, wc, acc4.w);
            acc4.x = fmaf(vd.x, wd, acc4.x); acc4.y = fmaf(vd.y, wd, acc4.y);
            acc4.z = fmaf(vd.z, wd, acc4.z); acc4.w = fmaf(vd.w, wd, acc4.w);
            acc4.x = fmaf(ve.x, we, acc4.x); acc4.y = fmaf(ve.y, we, acc4.y);
            acc4.z = fmaf(ve.z, we, acc4.z); acc4.w = fmaf(ve.w, we, acc4.w);
            acc4.x = fmaf(vf.x, wf, acc4.x); acc4.y = fmaf(vf.y, wf, acc4.y);
            acc4.z = fmaf(vf.z, wf, acc4.z); acc4.w = fmaf(vf.w, wf, acc4.w);
            acc4.x = fmaf(vg.x, wg, acc4.x); acc4.y = fmaf(vg.y, wg, acc4.y);
            acc4.z = fmaf(vg.z, wg, acc4.z); acc4.w = fmaf(vg.w, wg, acc4.w);
            acc4.x = fmaf(vh.x, wh, acc4.x); acc4.y = fmaf(vh.y, wh, acc4.y);
            acc4.z = fmaf(vh.z, wh, acc4.z); acc4.w = fmaf(vh.w, wh, acc4.w);
        }
        acc4.x += __shfl_xor(acc4.x, 16); acc4.y += __shfl_xor(acc4.y, 16);
        acc4.z += __shfl_xor(acc4.z, 16); acc4.w += __shfl_xor(acc4.w, 16);
        acc4.x += __shfl_xor(acc4.x, 32); acc4.y += __shfl_xor(acc4.y, 32);
        acc4.z += __shfl_xor(acc4.z, 32); acc4.w += __shfl_xor(acc4.w, 32);
        if (eslot == 0) *(float4*)(&a2[nn][q * 4]) = acc4;
        hrow[nn][c] = h[n * 64 + c];
        __syncthreads();
        // GEMV: 4 groups of 128 threads; group g computes nodes 2g, 2g+1 over full kk.
        int g = t >> 7, c2 = t & 127;
        if (c2 < NCLUST) {
            int na = 2 * g, nb2 = 2 * g + 1;
            float s0 = b2s[c2], s1 = s0;
#pragma unroll 8
            for (int kk = 0; kk < 64; ++kk) {
                float wr = wsrel[kk * 100 + c2];
                float wo = w2t_root[kk * 100 + c2];
                s0 = fmaf(a2[na][kk], wr, fmaf(hrow[na][kk], wo, s0));
                s1 = fmaf(a2[nb2][kk], wr, fmaf(hrow[nb2][kk], wo, s1));
            }
            logits[na][c2] = s0;
            logits[nb2][c2] = s1;
        }
        __syncthreads();
        float v0 = logits[nn][c];
        float v1 = (c < NCLUST - 64) ? logits[nn][64 + c] : -INFINITY;
        float m = fmaxf(v0, v1);
#pragma unroll
        for (int off = 32; off > 0; off >>= 1) m = fmaxf(m, __shfl_xor(m, off));
        float e0 = __expf(v0 - m);
        float e1 = (c < NCLUST - 64) ? __expf(v1 - m) : 0.f;
        float s = e0 + e1;
#pragma unroll
        for (int off = 32; off > 0; off >>= 1) s += __shfl_xor(s, off);
        float inv = 1.f / s;
        out[n * NCLUST + c] = e0 * inv;
        if (c < NCLUST - 64) out[n * NCLUST + 64 + c] = e1 * inv;
    } else {
        // ---- scalars mc, o (entries in t<256)
        float* red = wsrel;
        float sv = 0.f;
        if (t < 256)
            for (int bb = 0; bb < NBLK_N; ++bb) sv += sspart[bb * 256 + t];
        red[t] = sv * sv;
        __syncthreads();
        for (int s = 256; s > 0; s >>= 1) {
            if (t < s) red[t] += red[t + s];
            __syncthreads();
        }
        float ssnorm = sqrtf(red[0]);
        __syncthreads();
        float diff = (t < 256) ? (sv / ssnorm - ((t % 17 == 0) ? 0.25f : 0.f)) : 0.f;
        red[t] = diff * diff;
        __syncthreads();
        for (int s = 256; s > 0; s >>= 1) {
            if (t < s) red[t] += red[t + s];
            __syncthreads();
        }
        if (t == 0) {
            out[N_NODES * NCLUST + 0] = -(scal[0] / scal[1]);
            out[N_NODES * NCLUST + 1] = sqrtf(red[0]);
        }
    }
}

extern "C" void kernel_launch(void* const* d_in, const int* in_sizes, int n_in,
                              void* d_out, int out_size, void* d_ws, size_t ws_size,
                              hipStream_t stream) {
    const float* x       = (const float*)d_in[0];
    const int*   ei      = (const int*)d_in[1];
    const float* ew      = (const float*)d_in[2];
    const float* W1_rel  = (const float*)d_in[3];
    const float* W1_root = (const float*)d_in[4];
    const float* b1      = (const float*)d_in[5];
    const float* W2_rel  = (const float*)d_in[6];
    const float* W2_root = (const float*)d_in[7];
    const float* b2      = (const float*)d_in[8];
    float* out = (float*)d_out;
    int*   wsi = (int*)d_ws;

    int*   bincnt  = wsi + OFF_BINCNT;
    float* scal    = (float*)(wsi + OFF_SCAL);
    float* sspart  = (float*)(wsi + OFF_SSPART);
    float* norm2   = (float*)(wsi + OFF_NORM2);
    float* w2trel  = (float*)(wsi + OFF_W2TREL);
    float* w2troot = (float*)(wsi + OFF_W2TROOT);
    float* smc     = (float*)(wsi + OFF_SMC);
    float* h       = (float*)(wsi + OFF_H);
    int2*  binbuf  = (int2*)(wsi + OFF_BINBUF);

    hipMemsetAsync(wsi, 0, ZERO_ELEMS * sizeof(int), stream);
    binA_kernel<<<NBLK_E + NBLK_N + 2, 256, 0, stream>>>(x, ei, ew, smc, norm2, bincnt, binbuf,
                                                         W2_rel, W2_root, w2trel, w2troot);
    fused1_kernel<<<NBLK_F1 + NBLK_N + NBLK_ME, 512, 0, stream>>>(
        binbuf, bincnt, x, W1_rel, W1_root, b1, h, smc, sspart, ei, ew, norm2, scal);
    fused2_finalize_kernel<<<NBLK_F2 + 1, 512, 0, stream>>>(binbuf, bincnt, h, w2trel, w2troot,
                                                            b2, out, sspart, scal);
}

// Round 22
// 84.571 us; speedup vs baseline: 4.1958x; 1.0441x over previous
//
#include <hip/hip_runtime.h>
#include <math.h>

#define N_NODES 12000
#define F_INN 16
#define HIDD 64
#define NCLUST 100
#define NEDGE 384000
#define NBLK_N 47
#define CAP 96
#define LCAP 97            // padded LDS bucket stride (bank-conflict fix, r20-proven)
#define EPT 4
#define NBLK_E 375
#define NBLK_F1 (N_NODES / 8)          // 1500 (8 nodes/block, 512 thr)
#define NBLK_ME 188                    // mincut blocks at 512 thr, EPT 4 (guarded)
#define NBLK_F2 (N_NODES / 8)          // 1500
#define NBIN 188
#define BINW 64
#define BCAP 2560
#define STCAP 24

// ws layout (4-byte element offsets):
#define OFF_BINCNT  0        // 188 int (memset)
#define OFF_SCAL    188      // 2 f32   (memset)
#define ZERO_ELEMS  190
#define OFF_SSPART  192      // 12032 f32
#define OFF_NORM2   12224    // 12000 f32
#define OFF_W2TREL  24224    // 6400 f32
#define OFF_W2TROOT 30624    // 6400 f32
#define OFF_SMC     37024    // 192000 f32
#define OFF_H       229024   // 768000 f32
#define OFF_BINBUF  997024   // 188*2560 int2 (byte 3988096, 8B aligned)

// ---------------- pass A: edge binning | smc softmax+norm2 | W2 transpose (r21 exact)
__global__ void binA_kernel(const float* __restrict__ x, const int* __restrict__ ei,
                            const float* __restrict__ ew, float* __restrict__ smc,
                            float* __restrict__ norm2, int* __restrict__ bincnt,
                            int2* __restrict__ binbuf, const float* __restrict__ W2_rel,
                            const float* __restrict__ W2_root, float* __restrict__ w2t_rel,
                            float* __restrict__ w2t_root) {
    __shared__ int shmA[188 + 188 * STCAP * 2];
    int t = threadIdx.x;
    int b = blockIdx.x;
    if (b < NBLK_E) {
        int* scnt = shmA;
        int2* sbuf = (int2*)(shmA + 188);
        for (int i = t; i < 188; i += 256) scnt[i] = 0;
        __syncthreads();
        int tid = b * 256 + t;
        int e0 = tid * EPT;
        int4 sv = *(const int4*)(ei + e0);
        int4 dv = *(const int4*)(ei + NEDGE + e0);
        float4 wv = *(const float4*)(ew + e0);
        int s[EPT] = {sv.x, sv.y, sv.z, sv.w};
        int d[EPT] = {dv.x, dv.y, dv.z, dv.w};
        float w[EPT] = {wv.x, wv.y, wv.z, wv.w};
#pragma unroll
        for (int i = 0; i < EPT; ++i) {
            int bin = d[i] >> 6;
            int dl = d[i] & 63;
            int2 rec = make_int2(s[i] | (dl << 16), __float_as_int(w[i]));
            int pos = atomicAdd(&scnt[bin], 1);
            if (pos < STCAP) {
                sbuf[bin * STCAP + pos] = rec;
            } else {
                int base = atomicAdd(&bincnt[bin], 1);
                binbuf[bin * BCAP + base] = rec;
            }
        }
        __syncthreads();
        if (t < 188) {
            int k = scnt[t];
            if (k > STCAP) k = STCAP;
            if (k > 0) {
                int base = atomicAdd(&bincnt[t], k);
                for (int i = 0; i < k; ++i) binbuf[t * BCAP + base + i] = sbuf[t * STCAP + i];
            }
        }
    } else if (b < NBLK_E + NBLK_N) {
        int i = (b - NBLK_E) * 256 + t;
        if (i >= N_NODES) return;
        const float4* xr = (const float4*)(x + i * 16);
        float4 r0 = xr[0], r1 = xr[1], r2 = xr[2], r3 = xr[3];
        float v[16] = {r0.x, r0.y, r0.z, r0.w, r1.x, r1.y, r1.z, r1.w,
                       r2.x, r2.y, r2.z, r2.w, r3.x, r3.y, r3.z, r3.w};
        float m = v[0];
#pragma unroll
        for (int k = 1; k < 16; ++k) m = fmaxf(m, v[k]);
        float s = 0.f;
#pragma unroll
        for (int k = 0; k < 16; ++k) { v[k] = __expf(v[k] - m); s += v[k]; }
        float inv = 1.f / s;
        float n2 = 0.f;
#pragma unroll
        for (int k = 0; k < 16; ++k) { v[k] *= inv; n2 += v[k] * v[k]; }
        float4* so = (float4*)(smc + i * 16);
        so[0] = make_float4(v[0], v[1], v[2], v[3]);
        so[1] = make_float4(v[4], v[5], v[6], v[7]);
        so[2] = make_float4(v[8], v[9], v[10], v[11]);
        so[3] = make_float4(v[12], v[13], v[14], v[15]);
        norm2[i] = n2;
    } else {
        float* fl = (float*)shmA;
        const float* src = (b == NBLK_E + NBLK_N) ? W2_rel : W2_root;
        float* dst = (b == NBLK_E + NBLK_N) ? w2t_rel : w2t_root;
        for (int i = t; i < 6400; i += 256) fl[i] = src[i];
        __syncthreads();
        for (int j = t; j < 6400; j += 256) {
            int kk = j / 100, cl = j - kk * 100;
            dst[j] = fl[cl * 64 + kk];
        }
    }
}

// ---------------- fused1 direct-from-bins (r21 exact)
__global__ __launch_bounds__(512) void fused1_kernel(
    const int2* __restrict__ binbuf, const int* __restrict__ bincnt,
    const float* __restrict__ x, const float* __restrict__ W1_rel,
    const float* __restrict__ W1_root, const float* __restrict__ b1, float* __restrict__ h,
    const float* __restrict__ smc, float* __restrict__ sspart, const int* __restrict__ ei,
    const float* __restrict__ ew, const float* __restrict__ norm2, float* __restrict__ scal) {
    __shared__ int lb[8 * LCAP * 2 + 8];   // lbuck[8][97] int2 + cnt[8]  (6.2 KB)
    __shared__ float wrelT[1024], wrootT[1024], b1s[64];   // 8.5 KB
    __shared__ float shm[4352];            // ss rows / mincut red  (17.4 KB)
    int t = threadIdx.x;
    int b = blockIdx.x;
    if (b < NBLK_F1) {
        int2* lbuck = (int2*)lb;
        int* cnt = lb + 8 * LCAP * 2;
        for (int idx = t; idx < 1024; idx += 512) {
            int f = idx >> 4, k = idx & 15;
            wrelT[(k << 6) + f]  = W1_rel[idx];
            wrootT[(k << 6) + f] = W1_root[idx];
        }
        if (t < 64) b1s[t] = b1[t];
        if (t < 8) cnt[t] = 0;
        __syncthreads();
        int bin = b >> 3;
        int sub = b & 7;
        int nE = bincnt[bin];
        const int2* bp = binbuf + bin * BCAP;
        for (int i = t; i < nE; i += 512) {
            int2 rec = bp[i];
            int dl = rec.x >> 16;
            if ((dl >> 3) == sub) {
                int ln = dl & 7;
                int pos = atomicAdd(&cnt[ln], 1);
                if (pos < CAP) lbuck[ln * LCAP + pos] = make_int2(rec.x & 0xFFFF, rec.y);
            }
        }
        __syncthreads();
        int w = t >> 6, lane = t & 63;
        int j2 = lane >> 2;
        int q  = lane & 3;
        int n = b * 8 + w;
        int len = cnt[w];
        const int2* bucket = lbuck + w * LCAP;
        float4 acc4 = make_float4(0.f, 0.f, 0.f, 0.f);
        for (int k = 0; k < len; k += 32) {
            int ia = k + j2, ib = k + 16 + j2;
            int2 pa = bucket[ia];
            int2 pb = bucket[ib];
            if (ia >= len) pa = make_int2(0, 0);
            if (ib >= len) pb = make_int2(0, 0);
            float4 va = *(const float4*)(x + pa.x * 16 + q * 4);
            float4 vb = *(const float4*)(x + pb.x * 16 + q * 4);
            float wa = __int_as_float(pa.y), wb = __int_as_float(pb.y);
            acc4.x = fmaf(va.x, wa, acc4.x); acc4.y = fmaf(va.y, wa, acc4.y);
            acc4.z = fmaf(va.z, wa, acc4.z); acc4.w = fmaf(va.w, wa, acc4.w);
            acc4.x = fmaf(vb.x, wb, acc4.x); acc4.y = fmaf(vb.y, wb, acc4.y);
            acc4.z = fmaf(vb.z, wb, acc4.z); acc4.w = fmaf(vb.w, wb, acc4.w);
        }
        acc4.x += __shfl_xor(acc4.x, 4);  acc4.y += __shfl_xor(acc4.y, 4);
        acc4.z += __shfl_xor(acc4.z, 4);  acc4.w += __shfl_xor(acc4.w, 4);
        acc4.x += __shfl_xor(acc4.x, 8);  acc4.y += __shfl_xor(acc4.y, 8);
        acc4.z += __shfl_xor(acc4.z, 8);  acc4.w += __shfl_xor(acc4.w, 8);
        acc4.x += __shfl_xor(acc4.x, 16); acc4.y += __shfl_xor(acc4.y, 16);
        acc4.z += __shfl_xor(acc4.z, 16); acc4.w += __shfl_xor(acc4.w, 16);
        acc4.x += __shfl_xor(acc4.x, 32); acc4.y += __shfl_xor(acc4.y, 32);
        acc4.z += __shfl_xor(acc4.z, 32); acc4.w += __shfl_xor(acc4.w, 32);
        float xv = (lane < 16) ? x[n * 16 + lane] : 0.f;
        float o = b1s[lane];
#define F1STEP(KK, COMP) { float ag = __shfl(acc4.COMP, (KK) >> 2);            \
                           float xb = __shfl(xv, (KK));                        \
                           o = fmaf(ag, wrelT[((KK) << 6) + lane],             \
                                    fmaf(xb, wrootT[((KK) << 6) + lane], o)); }
        F1STEP(0, x)  F1STEP(1, y)  F1STEP(2, z)  F1STEP(3, w)
        F1STEP(4, x)  F1STEP(5, y)  F1STEP(6, z)  F1STEP(7, w)
        F1STEP(8, x)  F1STEP(9, y)  F1STEP(10, z) F1STEP(11, w)
        F1STEP(12, x) F1STEP(13, y) F1STEP(14, z) F1STEP(15, w)
#undef F1STEP
        h[n * 64 + lane] = fmaxf(o, 0.f);
    } else if (b < NBLK_F1 + NBLK_N) {
        int bb = b - NBLK_F1;
        float* rows = shm;
        int n = bb * 256 + t;
        if (t < 256) {
            float* rp = rows + t * 17;
            if (n < N_NODES) {
                const float4* sr = (const float4*)(smc + n * 16);
                float4 a0 = sr[0], a1 = sr[1], a2v = sr[2], a3 = sr[3];
                rp[0] = a0.x;  rp[1] = a0.y;  rp[2] = a0.z;  rp[3] = a0.w;
                rp[4] = a1.x;  rp[5] = a1.y;  rp[6] = a1.z;  rp[7] = a1.w;
                rp[8] = a2v.x; rp[9] = a2v.y; rp[10] = a2v.z; rp[11] = a2v.w;
                rp[12] = a3.x; rp[13] = a3.y; rp[14] = a3.z; rp[15] = a3.w;
            } else {
#pragma unroll
                for (int k = 0; k < 16; ++k) rp[k] = 0.f;
            }
        }
        __syncthreads();
        if (t < 256) {
            int a = t & 15, bq = t >> 4;
            float accs = 0.f;
#pragma unroll 4
            for (int r = 0; r < 256; ++r)
                accs = fmaf(rows[r * 17 + a], rows[r * 17 + bq], accs);
            sspart[bb * 256 + t] = accs;
        }
    } else {
        int tid = (b - NBLK_F1 - NBLK_N) * 512 + t;
        int e0 = tid * EPT;
        float np = 0.f, dp = 0.f;
        if (e0 < NEDGE) {
            int4 sv = *(const int4*)(ei + e0);
            int4 dv = *(const int4*)(ei + NEDGE + e0);
            float4 wv = *(const float4*)(ew + e0);
            int s[EPT] = {sv.x, sv.y, sv.z, sv.w};
            int d[EPT] = {dv.x, dv.y, dv.z, dv.w};
            float w[EPT] = {wv.x, wv.y, wv.z, wv.w};
#pragma unroll
            for (int i = 0; i < EPT; ++i) {
                const float4* ps = (const float4*)(smc + s[i] * 16);
                const float4* pd = (const float4*)(smc + d[i] * 16);
                float4 s0 = ps[0], s1 = ps[1], s2 = ps[2], s3 = ps[3];
                float4 d0 = pd[0], d1 = pd[1], d2 = pd[2], d3 = pd[3];
                float dot = s0.x * d0.x + s0.y * d0.y + s0.z * d0.z + s0.w * d0.w +
                            s1.x * d1.x + s1.y * d1.y + s1.z * d1.z + s1.w * d1.w +
                            s2.x * d2.x + s2.y * d2.y + s2.z * d2.z + s2.w * d2.w +
                            s3.x * d3.x + s3.y * d3.y + s3.z * d3.z + s3.w * d3.w;
                np = fmaf(w[i], dot, np);
                dp = fmaf(w[i], norm2[s[i]], dp);
            }
        }
        float* redn = shm;
        float* redd = shm + 512;
        redn[t] = np;
        redd[t] = dp;
        __syncthreads();
        for (int s2 = 256; s2 > 0; s2 >>= 1) {
            if (t < s2) { redn[t] += redn[t + s2]; redd[t] += redd[t + s2]; }
            __syncthreads();
        }
        if (t == 0) {
            atomicAdd(&scal[0], redn[0]);
            atomicAdd(&scal[1], redd[0]);
        }
    }
}

// ---------------- fused2 direct-from-bins + float4-broadcast GEMV | finalize
// ONLY change vs r21: a2/hrow stored as float4 arrays; GEMV reads them as float4
// broadcasts (1 ds_read_b128 per 4 kk vs 16 scalar reads). fmaf chain order = r21 exact.
__global__ __launch_bounds__(512) void fused2_finalize_kernel(
    const int2* __restrict__ binbuf, const int* __restrict__ bincnt,
    const float* __restrict__ h, const float* __restrict__ w2t_rel,
    const float* __restrict__ w2t_root, const float* __restrict__ b2, float* __restrict__ out,
    const float* __restrict__ sspart, const float* __restrict__ scal) {
    __shared__ float wsrel[6400];      // 25.6 KB; finalize reuses as red
    __shared__ int lb[8 * LCAP * 2 + 8];   // lbuck[8][97] int2 + cnt[8]  (6.2 KB)
    __shared__ float4 a2v[8][16];      // a2[8][64]
    __shared__ float4 hrowv[8][16];    // hrow[8][64]
    __shared__ float logits[8][104];
    __shared__ float b2s[104];
    float* hrow = (float*)hrowv;
    int t = threadIdx.x;
    int b = blockIdx.x;
    if (b < NBLK_F2) {
        int2* lbuck = (int2*)lb;
        int* cnt = lb + 8 * LCAP * 2;
        for (int i = t; i < 6400; i += 512) wsrel[i] = w2t_rel[i];
        if (t < NCLUST) b2s[t] = b2[t];
        if (t < 8) cnt[t] = 0;
        __syncthreads();
        int bin = b >> 3;
        int sub = b & 7;
        int nE = bincnt[bin];
        const int2* bp = binbuf + bin * BCAP;
        for (int i = t; i < nE; i += 512) {
            int2 rec = bp[i];
            int dl = rec.x >> 16;
            if ((dl >> 3) == sub) {
                int ln = dl & 7;
                int pos = atomicAdd(&cnt[ln], 1);
                if (pos < CAP) lbuck[ln * LCAP + pos] = make_int2(rec.x & 0xFFFF, rec.y);
            }
        }
        __syncthreads();
        int nn = t >> 6;
        int c = t & 63;
        int eslot = c >> 4;
        int q = c & 15;
        int n = b * 8 + nn;
        int len = cnt[nn];
        const int2* bucket = lbuck + nn * LCAP;
        float4 acc4 = make_float4(0.f, 0.f, 0.f, 0.f);
        for (int k = 0; k < len; k += 32) {
            int i0 = k + eslot,      i1 = k + 4 + eslot;
            int i2 = k + 8 + eslot,  i3 = k + 12 + eslot;
            int i4 = k + 16 + eslot, i5 = k + 20 + eslot;
            int i6 = k + 24 + eslot, i7 = k + 28 + eslot;
            int2 pa = bucket[i0]; int2 pb = bucket[i1];
            int2 pc = bucket[i2]; int2 pd = bucket[i3];
            int2 pe = bucket[i4]; int2 pf = bucket[i5];
            int2 pg = bucket[i6]; int2 ph = bucket[i7];
            if (i0 >= len) pa = make_int2(0, 0);
            if (i1 >= len) pb = make_int2(0, 0);
            if (i2 >= len) pc = make_int2(0, 0);
            if (i3 >= len) pd = make_int2(0, 0);
            if (i4 >= len) pe = make_int2(0, 0);
            if (i5 >= len) pf = make_int2(0, 0);
            if (i6 >= len) pg = make_int2(0, 0);
            if (i7 >= len) ph = make_int2(0, 0);
            float4 va = *(const float4*)(h + pa.x * 64 + q * 4);
            float4 vb = *(const float4*)(h + pb.x * 64 + q * 4);
            float4 vc = *(const float4*)(h + pc.x * 64 + q * 4);
            float4 vd = *(const float4*)(h + pd.x * 64 + q * 4);
            float4 ve = *(const float4*)(h + pe.x * 64 + q * 4);
            float4 vf = *(const float4*)(h + pf.x * 64 + q * 4);
            float4 vg = *(const float4*)(h + pg.x * 64 + q * 4);
            float4 vh = *(const float4*)(h + ph.x * 64 + q * 4);
            float wa = __int_as_float(pa.y), wb = __int_as_float(pb.y);
            float wc = __int_as_float(pc.y), wd = __int_as_float(pd.y);
            float we = __int_as_float(pe.y), wf = __int_as_float(pf.y);
            float wg = __int_as_float(pg.y), wh = __int_as_float(ph.y);
            acc4.x = fmaf(va.x, wa, acc4.x); acc4.y = fmaf(va.y, wa, acc4.y);
            acc4.z = fmaf(va.z, wa, acc4.z); acc4.w = fmaf(va.w, wa, acc4.w);
            acc4.x = fmaf(vb.x, wb, acc4.x); acc4.y = fmaf(vb.y, wb, acc4.y);
            acc4.z = fmaf(vb.z, wb, acc4.z); acc4.w = fmaf(vb.w, wb, acc4.w);
            acc4.x = fmaf(vc.x, wc, acc4.x); acc4.y = fmaf(vc.y, wc, acc4.y);
            acc4.z = fmaf(vc.z, wc, acc4.z); acc4.w = fmaf(vc.w, wc, acc4.w);
            acc4.x = fmaf(vd.x, wd, acc4.x); acc4.y = fmaf(vd.y, wd, acc4.y);
            acc4.z = fmaf(vd.z, wd, acc4.z); acc4.w = fmaf(vd.w, wd, acc4.w);
            acc4.x = fmaf(ve.x, we, acc4.x); acc4.y = fmaf(ve.y, we, acc4.y);
            acc4.z = fmaf(ve.z, we, acc4.z); acc4.w = fmaf(ve.w, we, acc4.w);
            acc4.x = fmaf(vf.x, wf, acc4.x); acc4.y = fmaf(vf.y, wf, acc4.y);
            acc4.z = fmaf(vf.z, wf, acc4.z); acc4.w = fmaf(vf.w, wf, acc4.w);
            acc4.x = fmaf(vg.x, wg, acc4.x); acc4.y = fmaf(vg.y, wg, acc4.y);
            acc4.z = fmaf(vg.z, wg, acc4.z); acc4.w = fmaf(vg.w, wg, acc4.w);
            acc4.x = fmaf(vh.x, wh, acc4.x); acc4.y = fmaf(vh.y, wh, acc4.y);
            acc4.z = fmaf(vh.z, wh, acc4.z); acc4.w = fmaf(vh.w, wh, acc4.w);
        }
        acc4.x += __shfl_xor(acc4.x, 16); acc4.y += __shfl_xor(acc4.y, 16);
        acc4.z += __shfl_xor(acc4.z, 16); acc4.w += __shfl_xor(acc4.w, 16);
        acc4.x += __shfl_xor(acc4.x, 32); acc4.y += __shfl_xor(acc4.y, 32);
        acc4.z += __shfl_xor(acc4.z, 32); acc4.w += __shfl_xor(acc4.w, 32);
        if (eslot == 0) a2v[nn][q] = acc4;
        hrow[nn * 64 + c] = h[n * 64 + c];
        __syncthreads();
        // GEMV: group g (128 thr) computes nodes 2g, 2g+1; weights coalesced (LDS/global),
        // a2/hrow via float4 broadcasts. fmaf chain = r21 exact kk order.
        int g = t >> 7, c2 = t & 127;
        if (c2 < NCLUST) {
            int na = 2 * g, nb2 = 2 * g + 1;
            float s0 = b2s[c2], s1 = s0;
#pragma unroll
            for (int q4 = 0; q4 < 16; ++q4) {
                float4 aa = a2v[na][q4],  ha = hrowv[na][q4];
                float4 ab = a2v[nb2][q4], hb = hrowv[nb2][q4];
                int kk = q4 * 4;
                float wr0 = wsrel[(kk + 0) * 100 + c2], wo0 = w2t_root[(kk + 0) * 100 + c2];
                float wr1 = wsrel[(kk + 1) * 100 + c2], wo1 = w2t_root[(kk + 1) * 100 + c2];
                float wr2 = wsrel[(kk + 2) * 100 + c2], wo2 = w2t_root[(kk + 2) * 100 + c2];
                float wr3 = wsrel[(kk + 3) * 100 + c2], wo3 = w2t_root[(kk + 3) * 100 + c2];
                s0 = fmaf(aa.x, wr0, fmaf(ha.x, wo0, s0));
                s1 = fmaf(ab.x, wr0, fmaf(hb.x, wo0, s1));
                s0 = fmaf(aa.y, wr1, fmaf(ha.y, wo1, s0));
                s1 = fmaf(ab.y, wr1, fmaf(hb.y, wo1, s1));
                s0 = fmaf(aa.z, wr2, fmaf(ha.z, wo2, s0));
                s1 = fmaf(ab.z, wr2, fmaf(hb.z, wo2, s1));
                s0 = fmaf(aa.w, wr3, fmaf(ha.w, wo3, s0));
                s1 = fmaf(ab.w, wr3, fmaf(hb.w, wo3, s1));
            }
            logits[na][c2] = s0;
            logits[nb2][c2] = s1;
        }
        __syncthreads();
        float v0 = logits[nn][c];
        float v1 = (c < NCLUST - 64) ? logits[nn][64 + c] : -INFINITY;
        float m = fmaxf(v0, v1);
#pragma unroll
        for (int off = 32; off > 0; off >>= 1) m = fmaxf(m, __shfl_xor(m, off));
        float e0 = __expf(v0 - m);
        float e1 = (c < NCLUST - 64) ? __expf(v1 - m) : 0.f;
        float s = e0 + e1;
#pragma unroll
        for (int off = 32; off > 0; off >>= 1) s += __shfl_xor(s, off);
        float inv = 1.f / s;
        out[n * NCLUST + c] = e0 * inv;
        if (c < NCLUST - 64) out[n * NCLUST + 64 + c] = e1 * inv;
    } else {
        float* red = wsrel;
        float sv = 0.f;
        if (t < 256)
            for (int bb = 0; bb < NBLK_N; ++bb) sv += sspart[bb * 256 + t];
        red[t] = sv * sv;
        __syncthreads();
        for (int s = 256; s > 0; s >>= 1) {
            if (t < s) red[t] += red[t + s];
            __syncthreads();
        }
        float ssnorm = sqrtf(red[0]);
        __syncthreads();
        float diff = (t < 256) ? (sv / ssnorm - ((t % 17 == 0) ? 0.25f : 0.f)) : 0.f;
        red[t] = diff * diff;
        __syncthreads();
        for (int s = 256; s > 0; s >>= 1) {
            if (t < s) red[t] += red[t + s];
            __syncthreads();
        }
        if (t == 0) {
            out[N_NODES * NCLUST + 0] = -(scal[0] / scal[1]);
            out[N_NODES * NCLUST + 1] = sqrtf(red[0]);
        }
    }
}

extern "C" void kernel_launch(void* const* d_in, const int* in_sizes, int n_in,
                              void* d_out, int out_size, void* d_ws, size_t ws_size,
                              hipStream_t stream) {
    const float* x       = (const float*)d_in[0];
    const int*   ei      = (const int*)d_in[1];
    const float* ew      = (const float*)d_in[2];
    const float* W1_rel  = (const float*)d_in[3];
    const float* W1_root = (const float*)d_in[4];
    const float* b1      = (const float*)d_in[5];
    const float* W2_rel  = (const float*)d_in[6];
    const float* W2_root = (const float*)d_in[7];
    const float* b2      = (const float*)d_in[8];
    float* out = (float*)d_out;
    int*   wsi = (int*)d_ws;

    int*   bincnt  = wsi + OFF_BINCNT;
    float* scal    = (float*)(wsi + OFF_SCAL);
    float* sspart  = (float*)(wsi + OFF_SSPART);
    float* norm2   = (float*)(wsi + OFF_NORM2);
    float* w2trel  = (float*)(wsi + OFF_W2TREL);
    float* w2troot = (float*)(wsi + OFF_W2TROOT);
    float* smc     = (float*)(wsi + OFF_SMC);
    float* h       = (float*)(wsi + OFF_H);
    int2*  binbuf  = (int2*)(wsi + OFF_BINBUF);

    hipMemsetAsync(wsi, 0, ZERO_ELEMS * sizeof(int), stream);
    binA_kernel<<<NBLK_E + NBLK_N + 2, 256, 0, stream>>>(x, ei, ew, smc, norm2, bincnt, binbuf,
                                                         W2_rel, W2_root, w2trel, w2troot);
    fused1_kernel<<<NBLK_F1 + NBLK_N + NBLK_ME, 512, 0, stream>>>(
        binbuf, bincnt, x, W1_rel, W1_root, b1, h, smc, sspart, ei, ew, norm2, scal);
    fused2_finalize_kernel<<<NBLK_F2 + 1, 512, 0, stream>>>(binbuf, bincnt, h, w2trel, w2troot,
                                                            b2, out, sspart, scal);
}